// Round 11
// baseline (80.249 us; speedup 1.0000x reference)
//
#include <hip/hip_runtime.h>

#define NQ   4096
#define NGRP 256
#define LL   64
#define DD   512

typedef __attribute__((ext_vector_type(8))) short short8v;
typedef __attribute__((ext_vector_type(4))) float f32x4;
typedef __attribute__((ext_vector_type(4))) unsigned short us4v;

#define SCALE 0.044194173824159216f

// float -> bf16 bits, round-to-nearest-even
static __device__ __forceinline__ unsigned short f2bf(float f) {
  union { float f; unsigned u; } x{f};
  unsigned r = x.u + 0x7fffu + ((x.u >> 16) & 1u);
  return (unsigned short)(r >> 16);
}
static __device__ __forceinline__ float bf2f(unsigned short h) {
  union { unsigned u; float f; } x{(unsigned)h << 16};
  return x.f;
}

// split fp32 float4 -> hi/lo bf16 into XOR-slot-swizzled LDS tile [rows][8 slots of us8]
static __device__ __forceinline__ void split_store(
    unsigned short* Hh, unsigned short* Hl, int r, int c4, float4 v) {
  int s = c4 >> 1, hf = c4 & 1;
  int base = (r * 8 + (s ^ (r & 7))) * 8 + hf * 4;
  unsigned short h0 = f2bf(v.x), h1 = f2bf(v.y), h2 = f2bf(v.z), h3 = f2bf(v.w);
  us4v hv = {h0, h1, h2, h3};
  us4v lv = {f2bf(v.x - bf2f(h0)), f2bf(v.y - bf2f(h1)),
             f2bf(v.z - bf2f(h2)), f2bf(v.w - bf2f(h3))};
  *(us4v*)(Hh + base) = hv;
  *(us4v*)(Hl + base) = lv;
}

// MFMA fragment load from swizzled LDS tile (8 slots/row)
static __device__ __forceinline__ short8v frag(const unsigned short* P, int r, int sl) {
  return *(const short8v*)(P + (r * 8 + (sl ^ (r & 7))) * 8);
}
// 16 slots/row variant
static __device__ __forceinline__ short8v frag16(const unsigned short* P, int r, int sl) {
  return *(const short8v*)(P + (r * 16 + (sl ^ (r & 7))) * 8);
}

// ---------------- merged prep (R9-validated) ----------------
// blocks [0,128): W2T = Wk @ Wq^T via 3-term split MFMA, single-bf16 output.
// blocks [128,2176): q fp32 -> bf16;  2176: starts;  2177-2178: b2 = Wk @ bq
__global__ __launch_bounds__(256) void k_prep(
    const float* __restrict__ q_in, const int* __restrict__ gid,
    const float* __restrict__ Wk, const float* __restrict__ Wq,
    const float* __restrict__ bq,
    unsigned short* __restrict__ qbf, int* __restrict__ starts,
    float* __restrict__ b2, unsigned short* __restrict__ w2t) {
  __shared__ __align__(16) unsigned short lds[4 * 64 * 64];  // 32 KB
  int b = blockIdx.x, t = threadIdx.x;
  if (b < 128) {
    unsigned short* Ah = lds;
    unsigned short* Al = lds + 4096;
    unsigned short* Bh = lds + 8192;
    unsigned short* Bl = lds + 12288;
    int lane = t & 63, wid = t >> 6;
    int wm = wid >> 1, wn = wid & 1;
    int n0 = (b & 15) * 64, m0 = (b >> 4) * 64;
    f32x4 acc[2][2];
    #pragma unroll
    for (int i = 0; i < 2; ++i)
      #pragma unroll
      for (int j = 0; j < 2; ++j) acc[i][j] = (f32x4){0.f,0.f,0.f,0.f};

    for (int k0 = 0; k0 < 512; k0 += 64) {
      __syncthreads();
      #pragma unroll
      for (int i = 0; i < 4; ++i) {
        int idx = i * 256 + t, r = idx >> 4, c4 = idx & 15;
        float4 vA = *(const float4*)&Wk[(size_t)(m0 + r) * 512 + k0 + c4 * 4];
        split_store(Ah, Al, r, c4, vA);
        float4 vB = *(const float4*)&Wq[(size_t)(n0 + r) * 512 + k0 + c4 * 4];
        split_store(Bh, Bl, r, c4, vB);
      }
      __syncthreads();
      #pragma unroll
      for (int kk = 0; kk < 2; ++kk) {
        int sl = kk * 4 + (lane >> 4);
        short8v aH[2], aL[2], bH[2], bL[2];
        #pragma unroll
        for (int fm = 0; fm < 2; ++fm) {
          int r = wm * 32 + fm * 16 + (lane & 15);
          aH[fm] = frag(Ah, r, sl); aL[fm] = frag(Al, r, sl);
        }
        #pragma unroll
        for (int fn = 0; fn < 2; ++fn) {
          int r = wn * 32 + fn * 16 + (lane & 15);
          bH[fn] = frag(Bh, r, sl); bL[fn] = frag(Bl, r, sl);
        }
        #pragma unroll
        for (int fm = 0; fm < 2; ++fm)
          #pragma unroll
          for (int fn = 0; fn < 2; ++fn) {
            acc[fm][fn] = __builtin_amdgcn_mfma_f32_16x16x32_bf16(aH[fm], bH[fn], acc[fm][fn], 0, 0, 0);
            acc[fm][fn] = __builtin_amdgcn_mfma_f32_16x16x32_bf16(aH[fm], bL[fn], acc[fm][fn], 0, 0, 0);
            acc[fm][fn] = __builtin_amdgcn_mfma_f32_16x16x32_bf16(aL[fm], bH[fn], acc[fm][fn], 0, 0, 0);
          }
      }
    }
    int cn = lane & 15, rq = lane >> 4;
    #pragma unroll
    for (int fm = 0; fm < 2; ++fm)
      #pragma unroll
      for (int fn = 0; fn < 2; ++fn)
        #pragma unroll
        for (int j = 0; j < 4; ++j) {
          int m = m0 + wm * 32 + fm * 16 + rq * 4 + j;
          int n = n0 + wn * 32 + fn * 16 + cn;
          w2t[(size_t)m * 1024 + n] = f2bf(acc[fm][fn][j]);
        }
  } else if (b < 2176) {
    int idx = (b - 128) * 256 + t;   // one uint4 (8 bf16) per thread
    const float* src = q_in + (size_t)idx * 8;
    float4 f0 = *(const float4*)src;
    float4 f1 = *(const float4*)(src + 4);
    uint4 pk;
    pk.x = (unsigned)f2bf(f0.x) | ((unsigned)f2bf(f0.y) << 16);
    pk.y = (unsigned)f2bf(f0.z) | ((unsigned)f2bf(f0.w) << 16);
    pk.z = (unsigned)f2bf(f1.x) | ((unsigned)f2bf(f1.y) << 16);
    pk.w = (unsigned)f2bf(f1.z) | ((unsigned)f2bf(f1.w) << 16);
    ((uint4*)qbf)[idx] = pk;
  } else if (b == 2176) {
    for (int g = t; g <= NGRP; g += 256) {
      int lo = 0, hi = NQ;
      while (lo < hi) { int mid = (lo + hi) >> 1; if (gid[mid] < g) lo = mid + 1; else hi = mid; }
      starts[g] = lo;
    }
  } else {
    int dd = (b - 2177) * 256 + t;
    if (dd < DD) {
      float s = 0.f;
      const float* row = Wk + (size_t)dd * DD;
      for (int j = 0; j < DD; j += 4) {
        float4 w = *(const float4*)&row[j];
        float4 bb = *(const float4*)&bq[j];
        s += w.x*bb.x + w.y*bb.y + w.z*bb.z + w.w*bb.w;
      }
      b2[dd] = s;
    }
  }
}

// ---------------- fused qt + scores: S_part[dq][n][l] ----------------
// Grid 1024: g = bx>>2, dq = bx&3. Per 32-query chunk:
//   phase A: qt_chunk[32][128] = qbf[rows] @ w2t[dq*128..+128] + b2  (MFMA,
//            16 staged K-rounds, bf16 out into LDS — bit-identical to R9's qt)
//   phase B: scores slice via 2-term K-split MFMA reading Q from LDS.
// All sync intra-block. No qt global round-trip.
__global__ __launch_bounds__(256) void k_qs(
    const unsigned short* __restrict__ qbf,    // [4096][1024] bf16
    const unsigned short* __restrict__ w2t,    // [512][1024] bf16
    const float* __restrict__ b2,
    const float* __restrict__ kk_, const int* __restrict__ starts,
    float* __restrict__ s_part) {
  int g = blockIdx.x >> 2, dq = blockIdx.x & 3;
  int t = threadIdx.x, lane = t & 63, wid = t >> 6;
  int s0 = starts[g], s1 = starts[g + 1];
  if (s0 >= s1) return;

  __shared__ __align__(16) unsigned short Qt_s[32 * 128];        // 8 KB, 16-slot rows
  __shared__ __align__(16) unsigned short stage[(32 + 128) * 64]; // 20 KB
  unsigned short* As = stage;            // QT phase: qbf tile 32x64  (4 KB)
  unsigned short* Bs = stage + 2048;     // QT phase: w2t tile 128x64 (16 KB)
  unsigned short* Kh = stage;            // scores phase: 64x64 (8 KB)
  unsigned short* Kl = stage + 4096;     // scores phase: 64x64 (8 KB)

  float* sp = s_part + (size_t)dq * NQ * LL;

  for (int cs = s0; cs < s1; cs += 32) {
    int qc = min(32, s1 - cs);

    // ---- phase A: qt chunk via MFMA ----
    f32x4 accq[2][2];
    #pragma unroll
    for (int i = 0; i < 2; ++i)
      #pragma unroll
      for (int j = 0; j < 2; ++j) accq[i][j] = (f32x4){0.f,0.f,0.f,0.f};

    for (int k0 = 0; k0 < 1024; k0 += 64) {
      __syncthreads();
      // stage A: 32 rows x 8 slots (zero-pad rows >= qc)
      {
        int r = t >> 3, s = t & 7;
        uint4 v = make_uint4(0,0,0,0);
        if (r < qc) v = *(const uint4*)(qbf + (size_t)(cs + r) * 1024 + k0 + s * 8);
        ((uint4*)As)[r * 8 + (s ^ (r & 7))] = v;
      }
      // stage B: 128 rows x 8 slots
      #pragma unroll
      for (int i = 0; i < 4; ++i) {
        int idx = i * 256 + t;
        int r = idx >> 3, s = idx & 7;
        ((uint4*)Bs)[r * 8 + (s ^ (r & 7))] =
            *(const uint4*)(w2t + (size_t)(dq * 128 + r) * 1024 + k0 + s * 8);
      }
      __syncthreads();
      #pragma unroll
      for (int kk = 0; kk < 2; ++kk) {
        int sl = kk * 4 + (lane >> 4);
        short8v aF[2], bF[2];
        #pragma unroll
        for (int fm = 0; fm < 2; ++fm)
          aF[fm] = frag(As, fm * 16 + (lane & 15), sl);
        #pragma unroll
        for (int fn = 0; fn < 2; ++fn)
          bF[fn] = frag(Bs, wid * 32 + fn * 16 + (lane & 15), sl);
        #pragma unroll
        for (int fm = 0; fm < 2; ++fm)
          #pragma unroll
          for (int fn = 0; fn < 2; ++fn)
            accq[fm][fn] = __builtin_amdgcn_mfma_f32_16x16x32_bf16(aF[fm], bF[fn], accq[fm][fn], 0, 0, 0);
      }
    }
    // epilogue: +b2, f2bf, into swizzled Qt_s[q][d_local]
    {
      int cn = lane & 15, rq = lane >> 4;
      #pragma unroll
      for (int fn = 0; fn < 2; ++fn) {
        int dl = wid * 32 + fn * 16 + cn;
        float bias = b2[dq * 128 + dl];
        #pragma unroll
        for (int fm = 0; fm < 2; ++fm)
          #pragma unroll
          for (int j = 0; j < 4; ++j) {
            int q = fm * 16 + rq * 4 + j;
            Qt_s[(q * 16 + ((dl >> 3) ^ (q & 7))) * 8 + (dl & 7)] =
                f2bf(accq[fm][fn][j] + bias);
          }
      }
    }

    // ---- phase B: scores slice (2-term K split vs LDS Q) ----
    f32x4 accs[2];
    accs[0] = (f32x4){0.f,0.f,0.f,0.f};
    accs[1] = (f32x4){0.f,0.f,0.f,0.f};

    #pragma unroll
    for (int kt = 0; kt < 2; ++kt) {
      int k0 = dq * 128 + kt * 64;
      __syncthreads();   // kt=0: Qt_s visible + last QT round done; kt=1: prior MFMA reads done
      #pragma unroll
      for (int i = 0; i < 4; ++i) {
        int idx = i * 256 + t, r = idx >> 4, c4 = idx & 15;
        float4 v = *(const float4*)&kk_[((size_t)g * LL + r) * DD + k0 + c4 * 4];
        split_store(Kh, Kl, r, c4, v);
      }
      __syncthreads();
      #pragma unroll
      for (int kk = 0; kk < 2; ++kk) {
        int sl8 = kk * 4 + (lane >> 4);
        int slQ = kt * 8 + kk * 4 + (lane >> 4);
        int rA = wid * 16 + (lane & 15);
        short8v aH = frag(Kh, rA, sl8), aL = frag(Kl, rA, sl8);
        #pragma unroll
        for (int fn = 0; fn < 2; ++fn) {
          short8v bF = frag16(Qt_s, fn * 16 + (lane & 15), slQ);
          accs[fn] = __builtin_amdgcn_mfma_f32_16x16x32_bf16(aH, bF, accs[fn], 0, 0, 0);
          accs[fn] = __builtin_amdgcn_mfma_f32_16x16x32_bf16(aL, bF, accs[fn], 0, 0, 0);
        }
      }
    }
    // write partial S (row-guarded)
    {
      int cq = lane & 15, rq = lane >> 4;
      #pragma unroll
      for (int fn = 0; fn < 2; ++fn) {
        int q = fn * 16 + cq;
        if (q < qc) {
          float* row = sp + (size_t)(cs + q) * LL;
          #pragma unroll
          for (int j = 0; j < 4; ++j)
            row[wid * 16 + rq * 4 + j] = accs[fn][j];
        }
      }
    }
    __syncthreads();   // protect Qt_s/stage before next chunk
  }
}

// ---------------- PV: sum partials + softmax + out (R9-validated) ----------------
// Grid 512: g = bx>>1, dh = bx&1. 256 threads = 4 waves. S_lds [q][l]-major.
__global__ __launch_bounds__(256) void k_pv2(
    const float* __restrict__ s_part, const float* __restrict__ vv_,
    const float* __restrict__ msk, const int* __restrict__ starts,
    float* __restrict__ out) {
  int g = blockIdx.x >> 1, dh = blockIdx.x & 1;
  int t = threadIdx.x, lane = t & 63, wid = t >> 6;
  int s0 = starts[g], s1 = starts[g + 1];
  if (s0 >= s1) return;

  __shared__ __align__(16) float S_lds[32][68];   // 8.7 KB
  __shared__ float bias_lds[LL];
  if (t < LL) bias_lds[t] = __expf(50.0f * (1.0f - msk[g * LL + t])) - 1.0f;

  const float* vb = vv_ + (size_t)g * LL * DD + dh * 256 + lane * 4;

  for (int cs = s0; cs < s1; cs += 32) {
    int qc = min(32, s1 - cs);
    __syncthreads();
    // sum 4 quarters + scale + bias -> S_lds[q][l]
    #pragma unroll
    for (int i = 0; i < 2; ++i) {
      int f = i * 256 + t;
      int q = f >> 4, l4 = f & 15;
      const float* p = s_part + (size_t)(cs + q) * LL + l4 * 4;
      float4 a0 = *(const float4*)p;
      float4 a1 = *(const float4*)(p + (size_t)NQ * LL);
      float4 a2 = *(const float4*)(p + (size_t)2 * NQ * LL);
      float4 a3 = *(const float4*)(p + (size_t)3 * NQ * LL);
      float4 r;
      r.x = (a0.x + a1.x + a2.x + a3.x) * SCALE - bias_lds[l4 * 4 + 0];
      r.y = (a0.y + a1.y + a2.y + a3.y) * SCALE - bias_lds[l4 * 4 + 1];
      r.z = (a0.z + a1.z + a2.z + a3.z) * SCALE - bias_lds[l4 * 4 + 2];
      r.w = (a0.w + a1.w + a2.w + a3.w) * SCALE - bias_lds[l4 * 4 + 3];
      *(float4*)&S_lds[q][l4 * 4] = r;
    }
    __syncthreads();
    // softmax per q over 64 l: 32 q x 8 lanes
    {
      int q = t >> 3, i = t & 7;
      float4 x0 = *(const float4*)&S_lds[q][i * 8];
      float4 x1 = *(const float4*)&S_lds[q][i * 8 + 4];
      float mx = fmaxf(fmaxf(fmaxf(x0.x, x0.y), fmaxf(x0.z, x0.w)),
                       fmaxf(fmaxf(x1.x, x1.y), fmaxf(x1.z, x1.w)));
      #pragma unroll
      for (int off = 1; off < 8; off <<= 1) mx = fmaxf(mx, __shfl_xor(mx, off, 8));
      float e0 = __expf(x0.x - mx), e1 = __expf(x0.y - mx);
      float e2 = __expf(x0.z - mx), e3 = __expf(x0.w - mx);
      float e4 = __expf(x1.x - mx), e5 = __expf(x1.y - mx);
      float e6 = __expf(x1.z - mx), e7 = __expf(x1.w - mx);
      float sum = ((e0 + e1) + (e2 + e3)) + ((e4 + e5) + (e6 + e7));
      #pragma unroll
      for (int off = 1; off < 8; off <<= 1) sum += __shfl_xor(sum, off, 8);
      float inv = 1.0f / sum;
      *(float4*)&S_lds[q][i * 8]     = make_float4(e0 * inv, e1 * inv, e2 * inv, e3 * inv);
      *(float4*)&S_lds[q][i * 8 + 4] = make_float4(e4 * inv, e5 * inv, e6 * inv, e7 * inv);
    }
    __syncthreads();
    // PV: wave wid -> queries wid*8..+7; lane -> d = dh*256 + lane*4..+3
    {
      float o[8][4];
      #pragma unroll
      for (int u = 0; u < 8; ++u)
        #pragma unroll
        for (int e = 0; e < 4; ++e) o[u][e] = 0.f;
      for (int l0 = 0; l0 < LL; l0 += 4) {
        float a_[8][4];
        #pragma unroll
        for (int u = 0; u < 8; ++u) {
          float4 av = *(const float4*)&S_lds[wid * 8 + u][l0];
          a_[u][0] = av.x; a_[u][1] = av.y; a_[u][2] = av.z; a_[u][3] = av.w;
        }
        #pragma unroll
        for (int e = 0; e < 4; ++e) {
          float4 vv = *(const float4*)&vb[(size_t)(l0 + e) * DD];
          #pragma unroll
          for (int u = 0; u < 8; ++u) {
            o[u][0] += a_[u][e] * vv.x;
            o[u][1] += a_[u][e] * vv.y;
            o[u][2] += a_[u][e] * vv.z;
            o[u][3] += a_[u][e] * vv.w;
          }
        }
      }
      #pragma unroll
      for (int u = 0; u < 8; ++u) {
        int q = wid * 8 + u;
        if (q < qc) {
          *(float4*)&out[(size_t)(cs + q) * DD + dh * 256 + lane * 4] =
              make_float4(o[u][0], o[u][1], o[u][2], o[u][3]);
        }
      }
    }
  }
}

extern "C" void kernel_launch(void* const* d_in, const int* in_sizes, int n_in,
                              void* d_out, int out_size, void* d_ws, size_t ws_size,
                              hipStream_t stream) {
  const float* q_in = (const float*)d_in[0];
  const float* k_in = (const float*)d_in[1];
  const float* v_in = (const float*)d_in[2];
  const float* m_in = (const float*)d_in[3];
  const int*   gid  = (const int*)d_in[4];
  const float* Wq   = (const float*)d_in[5];
  const float* bq   = (const float*)d_in[6];
  const float* Wk   = (const float*)d_in[7];
  // d_in[8] = bk: per-query constant on all scores -> cancels in softmax.
  float* out = (float*)d_out;

  // ws: w2t[1MB] | qbf[8MB] | b2[2KB] | starts[2KB] | s_part[4MB]
  unsigned short* w2t = (unsigned short*)d_ws;
  unsigned short* qbf = w2t + 512 * 1024;
  float* b2 = (float*)(qbf + 4096 * 1024);
  int* starts = (int*)(b2 + 512);
  float* s_part = (float*)(starts + 512);   // [4][4096][64]

  // 1) prep: w2t (0-127) + qbf (128-2175) + starts (2176) + b2 (2177-2178)
  k_prep<<<2179, 256, 0, stream>>>(q_in, gid, Wk, Wq, bq, qbf, starts, b2, w2t);
  // 2) fused qt + partial scores, 4-way d-split (1024 blocks)
  k_qs<<<NGRP * 4, 256, 0, stream>>>(qbf, w2t, b2, k_in, starts, s_part);
  // 3) sum + softmax + PV, 2-way d-split (512 blocks)
  k_pv2<<<NGRP * 2, 256, 0, stream>>>(s_part, v_in, m_in, starts, out);
}

// Round 13
// 64.319 us; speedup vs baseline: 1.2477x; 1.2477x over previous
//
#include <hip/hip_runtime.h>

#define NQ   4096
#define NGRP 256
#define LL   64
#define DD   512

typedef __attribute__((ext_vector_type(8))) short short8v;
typedef __attribute__((ext_vector_type(4))) float f32x4;
typedef __attribute__((ext_vector_type(4))) unsigned short us4v;

#define SCALE 0.044194173824159216f

// float -> bf16 bits, round-to-nearest-even
static __device__ __forceinline__ unsigned short f2bf(float f) {
  union { float f; unsigned u; } x{f};
  unsigned r = x.u + 0x7fffu + ((x.u >> 16) & 1u);
  return (unsigned short)(r >> 16);
}
static __device__ __forceinline__ float bf2f(unsigned short h) {
  union { unsigned u; float f; } x{(unsigned)h << 16};
  return x.f;
}

// async global->LDS 16B: lds dest is wave-uniform base + lane*16
static __device__ __forceinline__ void gload16(const void* g, void* lds_wave_base) {
  __builtin_amdgcn_global_load_lds(
      (const __attribute__((address_space(1))) void*)g,
      (__attribute__((address_space(3))) void*)lds_wave_base, 16, 0, 0);
}

// split fp32 float4 -> hi/lo bf16 into XOR-slot-swizzled LDS tile [rows][8 slots of us8]
static __device__ __forceinline__ void split_store(
    unsigned short* Hh, unsigned short* Hl, int r, int c4, float4 v) {
  int s = c4 >> 1, hf = c4 & 1;
  int base = (r * 8 + (s ^ (r & 7))) * 8 + hf * 4;
  unsigned short h0 = f2bf(v.x), h1 = f2bf(v.y), h2 = f2bf(v.z), h3 = f2bf(v.w);
  us4v hv = {h0, h1, h2, h3};
  us4v lv = {f2bf(v.x - bf2f(h0)), f2bf(v.y - bf2f(h1)),
             f2bf(v.z - bf2f(h2)), f2bf(v.w - bf2f(h3))};
  *(us4v*)(Hh + base) = hv;
  *(us4v*)(Hl + base) = lv;
}

// MFMA fragment load from swizzled LDS tile (8 slots/row)
static __device__ __forceinline__ short8v frag(const unsigned short* P, int r, int sl) {
  return *(const short8v*)(P + (r * 8 + (sl ^ (r & 7))) * 8);
}
// 16 slots/row variant (BK=128 tiles); XOR acts on low 3 slot bits
static __device__ __forceinline__ short8v frag16(const unsigned short* P, int r, int sl) {
  return *(const short8v*)(P + (r * 16 + (sl ^ (r & 7))) * 8);
}

// ---------------- merged prep (R9-validated, unchanged) ----------------
// blocks [0,128): W2T = Wk @ Wq^T via 3-term split MFMA, single-bf16 output.
// blocks [128,2176): q fp32 -> bf16;  2176: starts;  2177-2178: b2 = Wk @ bq
__global__ __launch_bounds__(256) void k_prep(
    const float* __restrict__ q_in, const int* __restrict__ gid,
    const float* __restrict__ Wk, const float* __restrict__ Wq,
    const float* __restrict__ bq,
    unsigned short* __restrict__ qbf, int* __restrict__ starts,
    float* __restrict__ b2, unsigned short* __restrict__ w2t) {
  __shared__ __align__(16) unsigned short lds[4 * 64 * 64];  // 32 KB
  int b = blockIdx.x, t = threadIdx.x;
  if (b < 128) {
    unsigned short* Ah = lds;
    unsigned short* Al = lds + 4096;
    unsigned short* Bh = lds + 8192;
    unsigned short* Bl = lds + 12288;
    int lane = t & 63, wid = t >> 6;
    int wm = wid >> 1, wn = wid & 1;
    int n0 = (b & 15) * 64, m0 = (b >> 4) * 64;
    f32x4 acc[2][2];
    #pragma unroll
    for (int i = 0; i < 2; ++i)
      #pragma unroll
      for (int j = 0; j < 2; ++j) acc[i][j] = (f32x4){0.f,0.f,0.f,0.f};

    for (int k0 = 0; k0 < 512; k0 += 64) {
      __syncthreads();
      #pragma unroll
      for (int i = 0; i < 4; ++i) {
        int idx = i * 256 + t, r = idx >> 4, c4 = idx & 15;
        float4 vA = *(const float4*)&Wk[(size_t)(m0 + r) * 512 + k0 + c4 * 4];
        split_store(Ah, Al, r, c4, vA);
        float4 vB = *(const float4*)&Wq[(size_t)(n0 + r) * 512 + k0 + c4 * 4];
        split_store(Bh, Bl, r, c4, vB);
      }
      __syncthreads();
      #pragma unroll
      for (int kk = 0; kk < 2; ++kk) {
        int sl = kk * 4 + (lane >> 4);
        short8v aH[2], aL[2], bH[2], bL[2];
        #pragma unroll
        for (int fm = 0; fm < 2; ++fm) {
          int r = wm * 32 + fm * 16 + (lane & 15);
          aH[fm] = frag(Ah, r, sl); aL[fm] = frag(Al, r, sl);
        }
        #pragma unroll
        for (int fn = 0; fn < 2; ++fn) {
          int r = wn * 32 + fn * 16 + (lane & 15);
          bH[fn] = frag(Bh, r, sl); bL[fn] = frag(Bl, r, sl);
        }
        #pragma unroll
        for (int fm = 0; fm < 2; ++fm)
          #pragma unroll
          for (int fn = 0; fn < 2; ++fn) {
            acc[fm][fn] = __builtin_amdgcn_mfma_f32_16x16x32_bf16(aH[fm], bH[fn], acc[fm][fn], 0, 0, 0);
            acc[fm][fn] = __builtin_amdgcn_mfma_f32_16x16x32_bf16(aH[fm], bL[fn], acc[fm][fn], 0, 0, 0);
            acc[fm][fn] = __builtin_amdgcn_mfma_f32_16x16x32_bf16(aL[fm], bH[fn], acc[fm][fn], 0, 0, 0);
          }
      }
    }
    int cn = lane & 15, rq = lane >> 4;
    #pragma unroll
    for (int fm = 0; fm < 2; ++fm)
      #pragma unroll
      for (int fn = 0; fn < 2; ++fn)
        #pragma unroll
        for (int j = 0; j < 4; ++j) {
          int m = m0 + wm * 32 + fm * 16 + rq * 4 + j;
          int n = n0 + wn * 32 + fn * 16 + cn;
          w2t[(size_t)m * 1024 + n] = f2bf(acc[fm][fn][j]);
        }
  } else if (b < 2176) {
    int idx = (b - 128) * 256 + t;   // one uint4 (8 bf16) per thread
    const float* src = q_in + (size_t)idx * 8;
    float4 f0 = *(const float4*)src;
    float4 f1 = *(const float4*)(src + 4);
    uint4 pk;
    pk.x = (unsigned)f2bf(f0.x) | ((unsigned)f2bf(f0.y) << 16);
    pk.y = (unsigned)f2bf(f0.z) | ((unsigned)f2bf(f0.w) << 16);
    pk.z = (unsigned)f2bf(f1.x) | ((unsigned)f2bf(f1.y) << 16);
    pk.w = (unsigned)f2bf(f1.z) | ((unsigned)f2bf(f1.w) << 16);
    ((uint4*)qbf)[idx] = pk;
  } else if (b == 2176) {
    for (int g = t; g <= NGRP; g += 256) {
      int lo = 0, hi = NQ;
      while (lo < hi) { int mid = (lo + hi) >> 1; if (gid[mid] < g) lo = mid + 1; else hi = mid; }
      starts[g] = lo;
    }
  } else {
    int dd = (b - 2177) * 256 + t;
    if (dd < DD) {
      float s = 0.f;
      const float* row = Wk + (size_t)dd * DD;
      for (int j = 0; j < DD; j += 4) {
        float4 w = *(const float4*)&row[j];
        float4 bb = *(const float4*)&bq[j];
        s += w.x*bb.x + w.y*bb.y + w.z*bb.z + w.w*bb.w;
      }
      b2[dd] = s;
    }
  }
}

// ---------------- qt = q @ W2 + b2: 1-term bf16 MFMA, BK=128, async staging ----
// As/Bs staged via global_load_lds with pre-swizzled source column:
// linear LDS slot idx -> (r = idx>>4, ssw = idx&15), source col = ssw ^ (r&7).
__global__ __launch_bounds__(256) void gemm_qt_mfma(
    const unsigned short* __restrict__ qbf,
    const unsigned short* __restrict__ w2t,
    const float* __restrict__ b2,
    unsigned short* __restrict__ qt) {
  __shared__ __align__(16) unsigned short As[64 * 128];  // 16 KB
  __shared__ __align__(16) unsigned short Bs[64 * 128];  // 16 KB
  int t = threadIdx.x;
  int lane = t & 63, wid = t >> 6;
  int wm = wid >> 1, wn = wid & 1;
  int n0 = blockIdx.x * 64, m0 = blockIdx.y * 64;

  f32x4 acc[2][2];
  #pragma unroll
  for (int i = 0; i < 2; ++i)
    #pragma unroll
    for (int j = 0; j < 2; ++j) acc[i][j] = (f32x4){0.f, 0.f, 0.f, 0.f};

  for (int k0 = 0; k0 < 1024; k0 += 128) {
    __syncthreads();   // prior MFMA ds_reads done before overwrite
    #pragma unroll
    for (int i = 0; i < 4; ++i) {
      int idx = i * 256 + t;            // uint4 slot
      int r = idx >> 4, ssw = idx & 15;
      int scol = ssw ^ (r & 7);
      gload16(qbf + (size_t)(m0 + r) * 1024 + k0 + scol * 8,
              (char*)As + (i * 256 + wid * 64) * 16);
      gload16(w2t + (size_t)(n0 + r) * 1024 + k0 + scol * 8,
              (char*)Bs + (i * 256 + wid * 64) * 16);
    }
    __syncthreads();   // drains vmcnt -> tiles complete
    #pragma unroll
    for (int kk = 0; kk < 4; ++kk) {
      short8v aF[2], bF[2];
      int sl = kk * 4 + (lane >> 4);
      #pragma unroll
      for (int fm = 0; fm < 2; ++fm)
        aF[fm] = frag16(As, wm * 32 + fm * 16 + (lane & 15), sl);
      #pragma unroll
      for (int fn = 0; fn < 2; ++fn)
        bF[fn] = frag16(Bs, wn * 32 + fn * 16 + (lane & 15), sl);
      #pragma unroll
      for (int fm = 0; fm < 2; ++fm)
        #pragma unroll
        for (int fn = 0; fn < 2; ++fn)
          acc[fm][fn] = __builtin_amdgcn_mfma_f32_16x16x32_bf16(aF[fm], bF[fn], acc[fm][fn], 0, 0, 0);
    }
  }
  int cn = lane & 15, rq = lane >> 4;
  #pragma unroll
  for (int fn = 0; fn < 2; ++fn) {
    int n = n0 + wn * 32 + fn * 16 + cn;
    float bias = b2[n];
    #pragma unroll
    for (int fm = 0; fm < 2; ++fm)
      #pragma unroll
      for (int j = 0; j < 4; ++j) {
        int m = m0 + wm * 32 + fm * 16 + rq * 4 + j;
        qt[(size_t)m * 512 + n] = f2bf(acc[fm][fn][j] + bias);
      }
  }
}

// ---------------- partial scores: S_part[dq][n][l] ----------------
// Grid 1024: g = bx>>2, dq = bx&3. K split 2-term (VALU staging, needs convert);
// Q staged via global_load_lds (rows >= qc read neighbor data, outputs guarded).
__global__ __launch_bounds__(256) void k_scores4(
    const unsigned short* __restrict__ qt,
    const float* __restrict__ kk_, const int* __restrict__ starts,
    float* __restrict__ s_part) {
  int g = blockIdx.x >> 2, dq = blockIdx.x & 3;
  int t = threadIdx.x, lane = t & 63, wl = t >> 6;
  int s0 = starts[g], s1 = starts[g + 1];
  if (s0 >= s1) return;

  __shared__ __align__(16) unsigned short Kh[64*64], Kl[64*64];  // 8 KB each
  __shared__ __align__(16) unsigned short Qs[32*64];             // 4 KB

  float* sp = s_part + (size_t)dq * NQ * LL;

  for (int cs = s0; cs < s1; cs += 32) {
    int qc = min(32, s1 - cs);
    f32x4 acc[2];
    acc[0] = (f32x4){0.f,0.f,0.f,0.f};
    acc[1] = (f32x4){0.f,0.f,0.f,0.f};

    #pragma unroll
    for (int kt = 0; kt < 2; ++kt) {
      int k0 = dq * 128 + kt * 64;
      __syncthreads();
      // K tile: fp32 -> split hi/lo (VALU)
      #pragma unroll
      for (int i = 0; i < 4; ++i) {
        int idx = i * 256 + t, r = idx >> 4, c4 = idx & 15;
        float4 v = *(const float4*)&kk_[((size_t)g * LL + r) * DD + k0 + c4 * 4];
        split_store(Kh, Kl, r, c4, v);
      }
      // Q tile: async direct-to-LDS, pre-swizzled source column.
      // Wave wl covers uint4 slots wl*64..wl*64+63 (one per lane).
      {
        int r = t >> 3, ssw = t & 7;
        int scol = ssw ^ (r & 7);
        gload16(qt + (size_t)(cs + r) * DD + k0 + scol * 8,
                (char*)Qs + wl * 64 * 16);
      }
      __syncthreads();
      #pragma unroll
      for (int kk = 0; kk < 2; ++kk) {
        int sl = kk * 4 + (lane >> 4);
        int rA = wl * 16 + (lane & 15);
        short8v aH = frag(Kh, rA, sl), aL = frag(Kl, rA, sl);
        #pragma unroll
        for (int fn = 0; fn < 2; ++fn) {
          short8v bF = frag(Qs, fn * 16 + (lane & 15), sl);
          acc[fn] = __builtin_amdgcn_mfma_f32_16x16x32_bf16(aH, bF, acc[fn], 0, 0, 0);
          acc[fn] = __builtin_amdgcn_mfma_f32_16x16x32_bf16(aL, bF, acc[fn], 0, 0, 0);
        }
      }
    }
    // write partial S (row-guarded)
    {
      int cq = lane & 15, rq = lane >> 4;
      #pragma unroll
      for (int fn = 0; fn < 2; ++fn) {
        int q = fn * 16 + cq;
        if (q < qc) {
          float* row = sp + (size_t)(cs + q) * LL;
          #pragma unroll
          for (int j = 0; j < 4; ++j)
            row[wl * 16 + rq * 4 + j] = acc[fn][j];
        }
      }
    }
  }
}

// ---------------- PV: sum partials + softmax + out (R9-validated) ----------------
__global__ __launch_bounds__(256) void k_pv2(
    const float* __restrict__ s_part, const float* __restrict__ vv_,
    const float* __restrict__ msk, const int* __restrict__ starts,
    float* __restrict__ out) {
  int g = blockIdx.x >> 1, dh = blockIdx.x & 1;
  int t = threadIdx.x, lane = t & 63, wid = t >> 6;
  int s0 = starts[g], s1 = starts[g + 1];
  if (s0 >= s1) return;

  __shared__ __align__(16) float S_lds[32][68];   // 8.7 KB
  __shared__ float bias_lds[LL];
  if (t < LL) bias_lds[t] = __expf(50.0f * (1.0f - msk[g * LL + t])) - 1.0f;

  const float* vb = vv_ + (size_t)g * LL * DD + dh * 256 + lane * 4;

  for (int cs = s0; cs < s1; cs += 32) {
    int qc = min(32, s1 - cs);
    __syncthreads();
    #pragma unroll
    for (int i = 0; i < 2; ++i) {
      int f = i * 256 + t;
      int q = f >> 4, l4 = f & 15;
      const float* p = s_part + (size_t)(cs + q) * LL + l4 * 4;
      float4 a0 = *(const float4*)p;
      float4 a1 = *(const float4*)(p + (size_t)NQ * LL);
      float4 a2 = *(const float4*)(p + (size_t)2 * NQ * LL);
      float4 a3 = *(const float4*)(p + (size_t)3 * NQ * LL);
      float4 r;
      r.x = (a0.x + a1.x + a2.x + a3.x) * SCALE - bias_lds[l4 * 4 + 0];
      r.y = (a0.y + a1.y + a2.y + a3.y) * SCALE - bias_lds[l4 * 4 + 1];
      r.z = (a0.z + a1.z + a2.z + a3.z) * SCALE - bias_lds[l4 * 4 + 2];
      r.w = (a0.w + a1.w + a2.w + a3.w) * SCALE - bias_lds[l4 * 4 + 3];
      *(float4*)&S_lds[q][l4 * 4] = r;
    }
    __syncthreads();
    {
      int q = t >> 3, i = t & 7;
      float4 x0 = *(const float4*)&S_lds[q][i * 8];
      float4 x1 = *(const float4*)&S_lds[q][i * 8 + 4];
      float mx = fmaxf(fmaxf(fmaxf(x0.x, x0.y), fmaxf(x0.z, x0.w)),
                       fmaxf(fmaxf(x1.x, x1.y), fmaxf(x1.z, x1.w)));
      #pragma unroll
      for (int off = 1; off < 8; off <<= 1) mx = fmaxf(mx, __shfl_xor(mx, off, 8));
      float e0 = __expf(x0.x - mx), e1 = __expf(x0.y - mx);
      float e2 = __expf(x0.z - mx), e3 = __expf(x0.w - mx);
      float e4 = __expf(x1.x - mx), e5 = __expf(x1.y - mx);
      float e6 = __expf(x1.z - mx), e7 = __expf(x1.w - mx);
      float sum = ((e0 + e1) + (e2 + e3)) + ((e4 + e5) + (e6 + e7));
      #pragma unroll
      for (int off = 1; off < 8; off <<= 1) sum += __shfl_xor(sum, off, 8);
      float inv = 1.0f / sum;
      *(float4*)&S_lds[q][i * 8]     = make_float4(e0 * inv, e1 * inv, e2 * inv, e3 * inv);
      *(float4*)&S_lds[q][i * 8 + 4] = make_float4(e4 * inv, e5 * inv, e6 * inv, e7 * inv);
    }
    __syncthreads();
    {
      float o[8][4];
      #pragma unroll
      for (int u = 0; u < 8; ++u)
        #pragma unroll
        for (int e = 0; e < 4; ++e) o[u][e] = 0.f;
      for (int l0 = 0; l0 < LL; l0 += 4) {
        float a_[8][4];
        #pragma unroll
        for (int u = 0; u < 8; ++u) {
          float4 av = *(const float4*)&S_lds[wid * 8 + u][l0];
          a_[u][0] = av.x; a_[u][1] = av.y; a_[u][2] = av.z; a_[u][3] = av.w;
        }
        #pragma unroll
        for (int e = 0; e < 4; ++e) {
          float4 vv = *(const float4*)&vb[(size_t)(l0 + e) * DD];
          #pragma unroll
          for (int u = 0; u < 8; ++u) {
            o[u][0] += a_[u][e] * vv.x;
            o[u][1] += a_[u][e] * vv.y;
            o[u][2] += a_[u][e] * vv.z;
            o[u][3] += a_[u][e] * vv.w;
          }
        }
      }
      #pragma unroll
      for (int u = 0; u < 8; ++u) {
        int q = wid * 8 + u;
        if (q < qc) {
          *(float4*)&out[(size_t)(cs + q) * DD + dh * 256 + lane * 4] =
              make_float4(o[u][0], o[u][1], o[u][2], o[u][3]);
        }
      }
    }
  }
}

extern "C" void kernel_launch(void* const* d_in, const int* in_sizes, int n_in,
                              void* d_out, int out_size, void* d_ws, size_t ws_size,
                              hipStream_t stream) {
  const float* q_in = (const float*)d_in[0];
  const float* k_in = (const float*)d_in[1];
  const float* v_in = (const float*)d_in[2];
  const float* m_in = (const float*)d_in[3];
  const int*   gid  = (const int*)d_in[4];
  const float* Wq   = (const float*)d_in[5];
  const float* bq   = (const float*)d_in[6];
  const float* Wk   = (const float*)d_in[7];
  // d_in[8] = bk: per-query constant on all scores -> cancels in softmax.
  float* out = (float*)d_out;

  // ws: w2t[1MB] | qt[4MB] | qbf[8MB] | b2[2KB] | starts[2KB] | s_part[4MB]
  unsigned short* w2t = (unsigned short*)d_ws;
  unsigned short* qt  = w2t + 512 * 1024;
  unsigned short* qbf = qt + 4096 * 512;
  float* b2 = (float*)(qbf + 4096 * 1024);
  int* starts = (int*)(b2 + 512);
  float* s_part = (float*)(starts + 512);   // [4][4096][64]

  // 1) prep: w2t (0-127) + qbf (128-2175) + starts (2176) + b2 (2177-2178)
  k_prep<<<2179, 256, 0, stream>>>(q_in, gid, Wk, Wq, bq, qbf, starts, b2, w2t);
  // 2) qt = q @ W2 + b2 (1-term, BK=128, async staging, bf16 out)
  gemm_qt_mfma<<<dim3(8, 64), 256, 0, stream>>>(qbf, w2t, b2, qt);
  // 3) partial scores, 4-way d-split (1024 blocks)
  k_scores4<<<NGRP * 4, 256, 0, stream>>>(qt, k_in, starts, s_part);
  // 4) sum + softmax + PV, 2-way d-split (512 blocks)
  k_pv2<<<NGRP * 2, 256, 0, stream>>>(s_part, v_in, m_in, starts, out);
}

// Round 14
// 64.129 us; speedup vs baseline: 1.2514x; 1.0030x over previous
//
#include <hip/hip_runtime.h>

#define NQ   4096
#define NGRP 256
#define LL   64
#define DD   512

typedef __attribute__((ext_vector_type(8))) short short8v;
typedef __attribute__((ext_vector_type(4))) float f32x4;
typedef __attribute__((ext_vector_type(4))) unsigned short us4v;

#define SCALE 0.044194173824159216f

// float -> bf16 bits, round-to-nearest-even
static __device__ __forceinline__ unsigned short f2bf(float f) {
  union { float f; unsigned u; } x{f};
  unsigned r = x.u + 0x7fffu + ((x.u >> 16) & 1u);
  return (unsigned short)(r >> 16);
}
static __device__ __forceinline__ float bf2f(unsigned short h) {
  union { unsigned u; float f; } x{(unsigned)h << 16};
  return x.f;
}

// async global->LDS 16B: lds dest is wave-uniform base + lane*16
static __device__ __forceinline__ void gload16(const void* g, void* lds_wave_base) {
  __builtin_amdgcn_global_load_lds(
      (const __attribute__((address_space(1))) void*)g,
      (__attribute__((address_space(3))) void*)lds_wave_base, 16, 0, 0);
}

// fp32 float4 pair -> packed 8 bf16 (uint4)
static __device__ __forceinline__ uint4 pack8(float4 f0, float4 f1) {
  uint4 pk;
  pk.x = (unsigned)f2bf(f0.x) | ((unsigned)f2bf(f0.y) << 16);
  pk.y = (unsigned)f2bf(f0.z) | ((unsigned)f2bf(f0.w) << 16);
  pk.z = (unsigned)f2bf(f1.x) | ((unsigned)f2bf(f1.y) << 16);
  pk.w = (unsigned)f2bf(f1.z) | ((unsigned)f2bf(f1.w) << 16);
  return pk;
}

// split fp32 float4 -> hi/lo bf16 into XOR-slot-swizzled LDS tile [rows][8 slots of us8]
static __device__ __forceinline__ void split_store(
    unsigned short* Hh, unsigned short* Hl, int r, int c4, float4 v) {
  int s = c4 >> 1, hf = c4 & 1;
  int base = (r * 8 + (s ^ (r & 7))) * 8 + hf * 4;
  unsigned short h0 = f2bf(v.x), h1 = f2bf(v.y), h2 = f2bf(v.z), h3 = f2bf(v.w);
  us4v hv = {h0, h1, h2, h3};
  us4v lv = {f2bf(v.x - bf2f(h0)), f2bf(v.y - bf2f(h1)),
             f2bf(v.z - bf2f(h2)), f2bf(v.w - bf2f(h3))};
  *(us4v*)(Hh + base) = hv;
  *(us4v*)(Hl + base) = lv;
}

// MFMA fragment load from swizzled LDS tile (8 slots/row)
static __device__ __forceinline__ short8v frag(const unsigned short* P, int r, int sl) {
  return *(const short8v*)(P + (r * 8 + (sl ^ (r & 7))) * 8);
}
// 16 slots/row variant (BK=128 tiles); XOR acts on low 3 slot bits
static __device__ __forceinline__ short8v frag16(const unsigned short* P, int r, int sl) {
  return *(const short8v*)(P + (r * 16 + (sl ^ (r & 7))) * 8);
}

// ---------------- merged prep ----------------
// blocks [0,128): W2T = Wk @ Wq^T via 3-term split MFMA, single-bf16 output.
// blocks [128,2176): q fp32 -> bf16;  2176: starts;  2177-2178: b2 = Wk @ bq;
// blocks [2179,6275): K fp32 -> bf16 (consumed only by k_scores4, so last).
__global__ __launch_bounds__(256) void k_prep(
    const float* __restrict__ q_in, const float* __restrict__ k_in,
    const int* __restrict__ gid,
    const float* __restrict__ Wk, const float* __restrict__ Wq,
    const float* __restrict__ bq,
    unsigned short* __restrict__ qbf, unsigned short* __restrict__ kbf,
    int* __restrict__ starts,
    float* __restrict__ b2, unsigned short* __restrict__ w2t) {
  __shared__ __align__(16) unsigned short lds[4 * 64 * 64];  // 32 KB
  int b = blockIdx.x, t = threadIdx.x;
  if (b < 128) {
    unsigned short* Ah = lds;
    unsigned short* Al = lds + 4096;
    unsigned short* Bh = lds + 8192;
    unsigned short* Bl = lds + 12288;
    int lane = t & 63, wid = t >> 6;
    int wm = wid >> 1, wn = wid & 1;
    int n0 = (b & 15) * 64, m0 = (b >> 4) * 64;
    f32x4 acc[2][2];
    #pragma unroll
    for (int i = 0; i < 2; ++i)
      #pragma unroll
      for (int j = 0; j < 2; ++j) acc[i][j] = (f32x4){0.f,0.f,0.f,0.f};

    for (int k0 = 0; k0 < 512; k0 += 64) {
      __syncthreads();
      #pragma unroll
      for (int i = 0; i < 4; ++i) {
        int idx = i * 256 + t, r = idx >> 4, c4 = idx & 15;
        float4 vA = *(const float4*)&Wk[(size_t)(m0 + r) * 512 + k0 + c4 * 4];
        split_store(Ah, Al, r, c4, vA);
        float4 vB = *(const float4*)&Wq[(size_t)(n0 + r) * 512 + k0 + c4 * 4];
        split_store(Bh, Bl, r, c4, vB);
      }
      __syncthreads();
      #pragma unroll
      for (int kk = 0; kk < 2; ++kk) {
        int sl = kk * 4 + (lane >> 4);
        short8v aH[2], aL[2], bH[2], bL[2];
        #pragma unroll
        for (int fm = 0; fm < 2; ++fm) {
          int r = wm * 32 + fm * 16 + (lane & 15);
          aH[fm] = frag(Ah, r, sl); aL[fm] = frag(Al, r, sl);
        }
        #pragma unroll
        for (int fn = 0; fn < 2; ++fn) {
          int r = wn * 32 + fn * 16 + (lane & 15);
          bH[fn] = frag(Bh, r, sl); bL[fn] = frag(Bl, r, sl);
        }
        #pragma unroll
        for (int fm = 0; fm < 2; ++fm)
          #pragma unroll
          for (int fn = 0; fn < 2; ++fn) {
            acc[fm][fn] = __builtin_amdgcn_mfma_f32_16x16x32_bf16(aH[fm], bH[fn], acc[fm][fn], 0, 0, 0);
            acc[fm][fn] = __builtin_amdgcn_mfma_f32_16x16x32_bf16(aH[fm], bL[fn], acc[fm][fn], 0, 0, 0);
            acc[fm][fn] = __builtin_amdgcn_mfma_f32_16x16x32_bf16(aL[fm], bH[fn], acc[fm][fn], 0, 0, 0);
          }
      }
    }
    int cn = lane & 15, rq = lane >> 4;
    #pragma unroll
    for (int fm = 0; fm < 2; ++fm)
      #pragma unroll
      for (int fn = 0; fn < 2; ++fn)
        #pragma unroll
        for (int j = 0; j < 4; ++j) {
          int m = m0 + wm * 32 + fm * 16 + rq * 4 + j;
          int n = n0 + wn * 32 + fn * 16 + cn;
          w2t[(size_t)m * 1024 + n] = f2bf(acc[fm][fn][j]);
        }
  } else if (b < 2176) {
    int idx = (b - 128) * 256 + t;   // one uint4 (8 bf16) per thread
    const float* src = q_in + (size_t)idx * 8;
    ((uint4*)qbf)[idx] = pack8(*(const float4*)src, *(const float4*)(src + 4));
  } else if (b == 2176) {
    for (int g = t; g <= NGRP; g += 256) {
      int lo = 0, hi = NQ;
      while (lo < hi) { int mid = (lo + hi) >> 1; if (gid[mid] < g) lo = mid + 1; else hi = mid; }
      starts[g] = lo;
    }
  } else if (b < 2179) {
    int dd = (b - 2177) * 256 + t;
    if (dd < DD) {
      float s = 0.f;
      const float* row = Wk + (size_t)dd * DD;
      for (int j = 0; j < DD; j += 4) {
        float4 w = *(const float4*)&row[j];
        float4 bb = *(const float4*)&bq[j];
        s += w.x*bb.x + w.y*bb.y + w.z*bb.z + w.w*bb.w;
      }
      b2[dd] = s;
    }
  } else {
    int idx = (b - 2179) * 256 + t;  // one uint4 (8 bf16) per thread, 4096 blocks
    const float* src = k_in + (size_t)idx * 8;
    ((uint4*)kbf)[idx] = pack8(*(const float4*)src, *(const float4*)(src + 4));
  }
}

// ---------------- qt = q @ W2 + b2: 1-term bf16 MFMA, BK=128, async staging ----
// (R13-validated, unchanged)
__global__ __launch_bounds__(256) void gemm_qt_mfma(
    const unsigned short* __restrict__ qbf,
    const unsigned short* __restrict__ w2t,
    const float* __restrict__ b2,
    unsigned short* __restrict__ qt) {
  __shared__ __align__(16) unsigned short As[64 * 128];  // 16 KB
  __shared__ __align__(16) unsigned short Bs[64 * 128];  // 16 KB
  int t = threadIdx.x;
  int lane = t & 63, wid = t >> 6;
  int wm = wid >> 1, wn = wid & 1;
  int n0 = blockIdx.x * 64, m0 = blockIdx.y * 64;

  f32x4 acc[2][2];
  #pragma unroll
  for (int i = 0; i < 2; ++i)
    #pragma unroll
    for (int j = 0; j < 2; ++j) acc[i][j] = (f32x4){0.f, 0.f, 0.f, 0.f};

  for (int k0 = 0; k0 < 1024; k0 += 128) {
    __syncthreads();   // prior MFMA ds_reads done before overwrite
    #pragma unroll
    for (int i = 0; i < 4; ++i) {
      int idx = i * 256 + t;            // uint4 slot
      int r = idx >> 4, ssw = idx & 15;
      int scol = ssw ^ (r & 7);
      gload16(qbf + (size_t)(m0 + r) * 1024 + k0 + scol * 8,
              (char*)As + (i * 256 + wid * 64) * 16);
      gload16(w2t + (size_t)(n0 + r) * 1024 + k0 + scol * 8,
              (char*)Bs + (i * 256 + wid * 64) * 16);
    }
    __syncthreads();   // drains vmcnt -> tiles complete
    #pragma unroll
    for (int kk = 0; kk < 4; ++kk) {
      short8v aF[2], bF[2];
      int sl = kk * 4 + (lane >> 4);
      #pragma unroll
      for (int fm = 0; fm < 2; ++fm)
        aF[fm] = frag16(As, wm * 32 + fm * 16 + (lane & 15), sl);
      #pragma unroll
      for (int fn = 0; fn < 2; ++fn)
        bF[fn] = frag16(Bs, wn * 32 + fn * 16 + (lane & 15), sl);
      #pragma unroll
      for (int fm = 0; fm < 2; ++fm)
        #pragma unroll
        for (int fn = 0; fn < 2; ++fn)
          acc[fm][fn] = __builtin_amdgcn_mfma_f32_16x16x32_bf16(aF[fm], bF[fn], acc[fm][fn], 0, 0, 0);
    }
  }
  int cn = lane & 15, rq = lane >> 4;
  #pragma unroll
  for (int fn = 0; fn < 2; ++fn) {
    int n = n0 + wn * 32 + fn * 16 + cn;
    float bias = b2[n];
    #pragma unroll
    for (int fm = 0; fm < 2; ++fm)
      #pragma unroll
      for (int j = 0; j < 4; ++j) {
        int m = m0 + wm * 32 + fm * 16 + rq * 4 + j;
        qt[(size_t)m * 512 + n] = f2bf(acc[fm][fn][j] + bias);
      }
  }
}

// ---------------- partial scores: S_part[dq][n][l] ----------------
// Grid 1024: g = bx>>2, dq = bx&3. FULLY async-staged: K (bf16, pre-converted)
// and Q both via global_load_lds with pre-swizzled source columns. 1-term
// bf16 x bf16 MFMA. LDS 12 KB.
__global__ __launch_bounds__(256) void k_scores4(
    const unsigned short* __restrict__ qt,
    const unsigned short* __restrict__ kbf, const int* __restrict__ starts,
    float* __restrict__ s_part) {
  int g = blockIdx.x >> 2, dq = blockIdx.x & 3;
  int t = threadIdx.x, lane = t & 63, wl = t >> 6;
  int s0 = starts[g], s1 = starts[g + 1];
  if (s0 >= s1) return;

  __shared__ __align__(16) unsigned short Ks[64*64];   // 8 KB
  __shared__ __align__(16) unsigned short Qs[32*64];   // 4 KB

  float* sp = s_part + (size_t)dq * NQ * LL;

  for (int cs = s0; cs < s1; cs += 32) {
    int qc = min(32, s1 - cs);
    f32x4 acc[2];
    acc[0] = (f32x4){0.f,0.f,0.f,0.f};
    acc[1] = (f32x4){0.f,0.f,0.f,0.f};

    #pragma unroll
    for (int kt = 0; kt < 2; ++kt) {
      int k0 = dq * 128 + kt * 64;
      __syncthreads();
      // K tile: async, 2 uint4 slots/thread, pre-swizzled source col
      #pragma unroll
      for (int i = 0; i < 2; ++i) {
        int idx = i * 256 + t;
        int r = idx >> 3, ssw = idx & 7;
        int scol = ssw ^ (r & 7);
        gload16(kbf + ((size_t)g * LL + r) * DD + k0 + scol * 8,
                (char*)Ks + (i * 256 + wl * 64) * 16);
      }
      // Q tile: async, 1 slot/thread (wave wl covers slots wl*64..+63)
      {
        int r = t >> 3, ssw = t & 7;
        int scol = ssw ^ (r & 7);
        gload16(qt + (size_t)(cs + r) * DD + k0 + scol * 8,
                (char*)Qs + wl * 64 * 16);
      }
      __syncthreads();
      #pragma unroll
      for (int kk = 0; kk < 2; ++kk) {
        int sl = kk * 4 + (lane >> 4);
        short8v aF = frag(Ks, wl * 16 + (lane & 15), sl);
        #pragma unroll
        for (int fn = 0; fn < 2; ++fn) {
          short8v bF = frag(Qs, fn * 16 + (lane & 15), sl);
          acc[fn] = __builtin_amdgcn_mfma_f32_16x16x32_bf16(aF, bF, acc[fn], 0, 0, 0);
        }
      }
    }
    // write partial S (row-guarded)
    {
      int cq = lane & 15, rq = lane >> 4;
      #pragma unroll
      for (int fn = 0; fn < 2; ++fn) {
        int q = fn * 16 + cq;
        if (q < qc) {
          float* row = sp + (size_t)(cs + q) * LL;
          #pragma unroll
          for (int j = 0; j < 4; ++j)
            row[wl * 16 + rq * 4 + j] = acc[fn][j];
        }
      }
    }
  }
}

// ---------------- PV: sum partials + softmax + out (R9-validated) ----------------
__global__ __launch_bounds__(256) void k_pv2(
    const float* __restrict__ s_part, const float* __restrict__ vv_,
    const float* __restrict__ msk, const int* __restrict__ starts,
    float* __restrict__ out) {
  int g = blockIdx.x >> 1, dh = blockIdx.x & 1;
  int t = threadIdx.x, lane = t & 63, wid = t >> 6;
  int s0 = starts[g], s1 = starts[g + 1];
  if (s0 >= s1) return;

  __shared__ __align__(16) float S_lds[32][68];   // 8.7 KB
  __shared__ float bias_lds[LL];
  if (t < LL) bias_lds[t] = __expf(50.0f * (1.0f - msk[g * LL + t])) - 1.0f;

  const float* vb = vv_ + (size_t)g * LL * DD + dh * 256 + lane * 4;

  for (int cs = s0; cs < s1; cs += 32) {
    int qc = min(32, s1 - cs);
    __syncthreads();
    #pragma unroll
    for (int i = 0; i < 2; ++i) {
      int f = i * 256 + t;
      int q = f >> 4, l4 = f & 15;
      const float* p = s_part + (size_t)(cs + q) * LL + l4 * 4;
      float4 a0 = *(const float4*)p;
      float4 a1 = *(const float4*)(p + (size_t)NQ * LL);
      float4 a2 = *(const float4*)(p + (size_t)2 * NQ * LL);
      float4 a3 = *(const float4*)(p + (size_t)3 * NQ * LL);
      float4 r;
      r.x = (a0.x + a1.x + a2.x + a3.x) * SCALE - bias_lds[l4 * 4 + 0];
      r.y = (a0.y + a1.y + a2.y + a3.y) * SCALE - bias_lds[l4 * 4 + 1];
      r.z = (a0.z + a1.z + a2.z + a3.z) * SCALE - bias_lds[l4 * 4 + 2];
      r.w = (a0.w + a1.w + a2.w + a3.w) * SCALE - bias_lds[l4 * 4 + 3];
      *(float4*)&S_lds[q][l4 * 4] = r;
    }
    __syncthreads();
    {
      int q = t >> 3, i = t & 7;
      float4 x0 = *(const float4*)&S_lds[q][i * 8];
      float4 x1 = *(const float4*)&S_lds[q][i * 8 + 4];
      float mx = fmaxf(fmaxf(fmaxf(x0.x, x0.y), fmaxf(x0.z, x0.w)),
                       fmaxf(fmaxf(x1.x, x1.y), fmaxf(x1.z, x1.w)));
      #pragma unroll
      for (int off = 1; off < 8; off <<= 1) mx = fmaxf(mx, __shfl_xor(mx, off, 8));
      float e0 = __expf(x0.x - mx), e1 = __expf(x0.y - mx);
      float e2 = __expf(x0.z - mx), e3 = __expf(x0.w - mx);
      float e4 = __expf(x1.x - mx), e5 = __expf(x1.y - mx);
      float e6 = __expf(x1.z - mx), e7 = __expf(x1.w - mx);
      float sum = ((e0 + e1) + (e2 + e3)) + ((e4 + e5) + (e6 + e7));
      #pragma unroll
      for (int off = 1; off < 8; off <<= 1) sum += __shfl_xor(sum, off, 8);
      float inv = 1.0f / sum;
      *(float4*)&S_lds[q][i * 8]     = make_float4(e0 * inv, e1 * inv, e2 * inv, e3 * inv);
      *(float4*)&S_lds[q][i * 8 + 4] = make_float4(e4 * inv, e5 * inv, e6 * inv, e7 * inv);
    }
    __syncthreads();
    {
      float o[8][4];
      #pragma unroll
      for (int u = 0; u < 8; ++u)
        #pragma unroll
        for (int e = 0; e < 4; ++e) o[u][e] = 0.f;
      for (int l0 = 0; l0 < LL; l0 += 4) {
        float a_[8][4];
        #pragma unroll
        for (int u = 0; u < 8; ++u) {
          float4 av = *(const float4*)&S_lds[wid * 8 + u][l0];
          a_[u][0] = av.x; a_[u][1] = av.y; a_[u][2] = av.z; a_[u][3] = av.w;
        }
        #pragma unroll
        for (int e = 0; e < 4; ++e) {
          float4 vv = *(const float4*)&vb[(size_t)(l0 + e) * DD];
          #pragma unroll
          for (int u = 0; u < 8; ++u) {
            o[u][0] += a_[u][e] * vv.x;
            o[u][1] += a_[u][e] * vv.y;
            o[u][2] += a_[u][e] * vv.z;
            o[u][3] += a_[u][e] * vv.w;
          }
        }
      }
      #pragma unroll
      for (int u = 0; u < 8; ++u) {
        int q = wid * 8 + u;
        if (q < qc) {
          *(float4*)&out[(size_t)(cs + q) * DD + dh * 256 + lane * 4] =
              make_float4(o[u][0], o[u][1], o[u][2], o[u][3]);
        }
      }
    }
  }
}

extern "C" void kernel_launch(void* const* d_in, const int* in_sizes, int n_in,
                              void* d_out, int out_size, void* d_ws, size_t ws_size,
                              hipStream_t stream) {
  const float* q_in = (const float*)d_in[0];
  const float* k_in = (const float*)d_in[1];
  const float* v_in = (const float*)d_in[2];
  const float* m_in = (const float*)d_in[3];
  const int*   gid  = (const int*)d_in[4];
  const float* Wq   = (const float*)d_in[5];
  const float* bq   = (const float*)d_in[6];
  const float* Wk   = (const float*)d_in[7];
  // d_in[8] = bk: per-query constant on all scores -> cancels in softmax.
  float* out = (float*)d_out;

  // ws: w2t[1MB] | qt[4MB] | qbf[8MB] | b2 | starts | s_part[4MB] | kbf[16.8MB]
  unsigned short* w2t = (unsigned short*)d_ws;
  unsigned short* qt  = w2t + 512 * 1024;
  unsigned short* qbf = qt + 4096 * 512;
  float* b2 = (float*)(qbf + 4096 * 1024);
  int* starts = (int*)(b2 + 512);
  float* s_part = (float*)(starts + 512);          // [4][4096][64]
  unsigned short* kbf = (unsigned short*)(s_part + 4 * NQ * LL);  // [256][64][512]

  // 1) prep: w2t (0-127) + qbf (128-2175) + starts (2176) + b2 (2177-2178)
  //    + kbf (2179-6274, last: only k_scores4 consumes it)
  k_prep<<<6275, 256, 0, stream>>>(q_in, k_in, gid, Wk, Wq, bq,
                                   qbf, kbf, starts, b2, w2t);
  // 2) qt = q @ W2 + b2 (1-term, BK=128, async staging, bf16 out)
  gemm_qt_mfma<<<dim3(8, 64), 256, 0, stream>>>(qbf, w2t, b2, qt);
  // 3) partial scores, fully async-staged, 4-way d-split (1024 blocks)
  k_scores4<<<NGRP * 4, 256, 0, stream>>>(qt, kbf, starts, s_part);
  // 4) sum + softmax + PV, 2-way d-split (512 blocks)
  k_pv2<<<NGRP * 2, 256, 0, stream>>>(s_part, v_in, m_in, starts, out);
}

// Round 15
// 60.392 us; speedup vs baseline: 1.3288x; 1.0619x over previous
//
#include <hip/hip_runtime.h>

#define NQ   4096
#define NGRP 256
#define LL   64
#define DD   512

typedef __attribute__((ext_vector_type(8))) short short8v;
typedef __attribute__((ext_vector_type(4))) float f32x4;
typedef __attribute__((ext_vector_type(4))) unsigned short us4v;

#define SCALE 0.044194173824159216f

// float -> bf16 bits, round-to-nearest-even
static __device__ __forceinline__ unsigned short f2bf(float f) {
  union { float f; unsigned u; } x{f};
  unsigned r = x.u + 0x7fffu + ((x.u >> 16) & 1u);
  return (unsigned short)(r >> 16);
}
static __device__ __forceinline__ float bf2f(unsigned short h) {
  union { unsigned u; float f; } x{(unsigned)h << 16};
  return x.f;
}

// async global->LDS 16B: lds dest is wave-uniform base + lane*16
static __device__ __forceinline__ void gload16(const void* g, void* lds_wave_base) {
  __builtin_amdgcn_global_load_lds(
      (const __attribute__((address_space(1))) void*)g,
      (__attribute__((address_space(3))) void*)lds_wave_base, 16, 0, 0);
}

// fp32 float4 pair -> packed 8 bf16 (uint4)
static __device__ __forceinline__ uint4 pack8(float4 f0, float4 f1) {
  uint4 pk;
  pk.x = (unsigned)f2bf(f0.x) | ((unsigned)f2bf(f0.y) << 16);
  pk.y = (unsigned)f2bf(f0.z) | ((unsigned)f2bf(f0.w) << 16);
  pk.z = (unsigned)f2bf(f1.x) | ((unsigned)f2bf(f1.y) << 16);
  pk.w = (unsigned)f2bf(f1.z) | ((unsigned)f2bf(f1.w) << 16);
  return pk;
}

// split fp32 float4 -> hi/lo bf16 into XOR-slot-swizzled LDS tile [rows][8 slots of us8]
static __device__ __forceinline__ void split_store(
    unsigned short* Hh, unsigned short* Hl, int r, int c4, float4 v) {
  int s = c4 >> 1, hf = c4 & 1;
  int base = (r * 8 + (s ^ (r & 7))) * 8 + hf * 4;
  unsigned short h0 = f2bf(v.x), h1 = f2bf(v.y), h2 = f2bf(v.z), h3 = f2bf(v.w);
  us4v hv = {h0, h1, h2, h3};
  us4v lv = {f2bf(v.x - bf2f(h0)), f2bf(v.y - bf2f(h1)),
             f2bf(v.z - bf2f(h2)), f2bf(v.w - bf2f(h3))};
  *(us4v*)(Hh + base) = hv;
  *(us4v*)(Hl + base) = lv;
}

// MFMA fragment load from swizzled LDS tile (8 slots/row)
static __device__ __forceinline__ short8v frag(const unsigned short* P, int r, int sl) {
  return *(const short8v*)(P + (r * 8 + (sl ^ (r & 7))) * 8);
}
// 16 slots/row variant (BK=128 tiles); XOR acts on low 3 slot bits
static __device__ __forceinline__ short8v frag16(const unsigned short* P, int r, int sl) {
  return *(const short8v*)(P + (r * 16 + (sl ^ (r & 7))) * 8);
}

// ---------------- merged prep (R13-validated layout) ----------------
// blocks [0,128): W2T = Wk @ Wq^T via 3-term split MFMA, single-bf16 output.
// blocks [128,2176): q fp32 -> bf16;  2176: starts;  2177-2178: b2 = Wk @ bq
__global__ __launch_bounds__(256) void k_prep(
    const float* __restrict__ q_in, const int* __restrict__ gid,
    const float* __restrict__ Wk, const float* __restrict__ Wq,
    const float* __restrict__ bq,
    unsigned short* __restrict__ qbf, int* __restrict__ starts,
    float* __restrict__ b2, unsigned short* __restrict__ w2t) {
  __shared__ __align__(16) unsigned short lds[4 * 64 * 64];  // 32 KB
  int b = blockIdx.x, t = threadIdx.x;
  if (b < 128) {
    unsigned short* Ah = lds;
    unsigned short* Al = lds + 4096;
    unsigned short* Bh = lds + 8192;
    unsigned short* Bl = lds + 12288;
    int lane = t & 63, wid = t >> 6;
    int wm = wid >> 1, wn = wid & 1;
    int n0 = (b & 15) * 64, m0 = (b >> 4) * 64;
    f32x4 acc[2][2];
    #pragma unroll
    for (int i = 0; i < 2; ++i)
      #pragma unroll
      for (int j = 0; j < 2; ++j) acc[i][j] = (f32x4){0.f,0.f,0.f,0.f};

    for (int k0 = 0; k0 < 512; k0 += 64) {
      __syncthreads();
      #pragma unroll
      for (int i = 0; i < 4; ++i) {
        int idx = i * 256 + t, r = idx >> 4, c4 = idx & 15;
        float4 vA = *(const float4*)&Wk[(size_t)(m0 + r) * 512 + k0 + c4 * 4];
        split_store(Ah, Al, r, c4, vA);
        float4 vB = *(const float4*)&Wq[(size_t)(n0 + r) * 512 + k0 + c4 * 4];
        split_store(Bh, Bl, r, c4, vB);
      }
      __syncthreads();
      #pragma unroll
      for (int kk = 0; kk < 2; ++kk) {
        int sl = kk * 4 + (lane >> 4);
        short8v aH[2], aL[2], bH[2], bL[2];
        #pragma unroll
        for (int fm = 0; fm < 2; ++fm) {
          int r = wm * 32 + fm * 16 + (lane & 15);
          aH[fm] = frag(Ah, r, sl); aL[fm] = frag(Al, r, sl);
        }
        #pragma unroll
        for (int fn = 0; fn < 2; ++fn) {
          int r = wn * 32 + fn * 16 + (lane & 15);
          bH[fn] = frag(Bh, r, sl); bL[fn] = frag(Bl, r, sl);
        }
        #pragma unroll
        for (int fm = 0; fm < 2; ++fm)
          #pragma unroll
          for (int fn = 0; fn < 2; ++fn) {
            acc[fm][fn] = __builtin_amdgcn_mfma_f32_16x16x32_bf16(aH[fm], bH[fn], acc[fm][fn], 0, 0, 0);
            acc[fm][fn] = __builtin_amdgcn_mfma_f32_16x16x32_bf16(aH[fm], bL[fn], acc[fm][fn], 0, 0, 0);
            acc[fm][fn] = __builtin_amdgcn_mfma_f32_16x16x32_bf16(aL[fm], bH[fn], acc[fm][fn], 0, 0, 0);
          }
      }
    }
    int cn = lane & 15, rq = lane >> 4;
    #pragma unroll
    for (int fm = 0; fm < 2; ++fm)
      #pragma unroll
      for (int fn = 0; fn < 2; ++fn)
        #pragma unroll
        for (int j = 0; j < 4; ++j) {
          int m = m0 + wm * 32 + fm * 16 + rq * 4 + j;
          int n = n0 + wn * 32 + fn * 16 + cn;
          w2t[(size_t)m * 1024 + n] = f2bf(acc[fm][fn][j]);
        }
  } else if (b < 2176) {
    int idx = (b - 128) * 256 + t;   // one uint4 (8 bf16) per thread
    const float* src = q_in + (size_t)idx * 8;
    ((uint4*)qbf)[idx] = pack8(*(const float4*)src, *(const float4*)(src + 4));
  } else if (b == 2176) {
    for (int g = t; g <= NGRP; g += 256) {
      int lo = 0, hi = NQ;
      while (lo < hi) { int mid = (lo + hi) >> 1; if (gid[mid] < g) lo = mid + 1; else hi = mid; }
      starts[g] = lo;
    }
  } else {
    int dd = (b - 2177) * 256 + t;
    if (dd < DD) {
      float s = 0.f;
      const float* row = Wk + (size_t)dd * DD;
      for (int j = 0; j < DD; j += 4) {
        float4 w = *(const float4*)&row[j];
        float4 bb = *(const float4*)&bq[j];
        s += w.x*bb.x + w.y*bb.y + w.z*bb.z + w.w*bb.w;
      }
      b2[dd] = s;
    }
  }
}

// ---------------- qt GEMM (XCD-swizzled) + K->bf16 conversion (trailing) ------
// blocks [0,512): qt = q @ W2 + b2, 1-term bf16 MFMA, BK=128, async staging.
//   XCD swizzle: logical = (b&7)*64 + (b>>3) -> each XCD gets a contiguous
//   m0-chunk x all n0 -> qbf/w2t L2-resident per XCD (vs 8x HBM re-fetch).
// blocks [512,4608): K fp32 -> bf16 (kbf). Rides HBM left idle by MFMA blocks;
//   consumed only by k_scores4 (next launch) -> dependency intact.
__global__ __launch_bounds__(256) void gemm_qt_mfma(
    const unsigned short* __restrict__ qbf,
    const unsigned short* __restrict__ w2t,
    const float* __restrict__ b2,
    unsigned short* __restrict__ qt,
    const float* __restrict__ k_in, unsigned short* __restrict__ kbf) {
  __shared__ __align__(16) unsigned short As[64 * 128];  // 16 KB
  __shared__ __align__(16) unsigned short Bs[64 * 128];  // 16 KB
  int b = blockIdx.x, t = threadIdx.x;

  if (b >= 512) {
    int idx = (b - 512) * 256 + t;   // one uint4 (8 bf16) per thread
    const float* src = k_in + (size_t)idx * 8;
    ((uint4*)kbf)[idx] = pack8(*(const float4*)src, *(const float4*)(src + 4));
    return;
  }

  int logical = (b & 7) * 64 + (b >> 3);       // bijective bit-permute
  int n0 = (logical & 7) * 64, m0 = (logical >> 3) * 64;
  int lane = t & 63, wid = t >> 6;
  int wm = wid >> 1, wn = wid & 1;

  f32x4 acc[2][2];
  #pragma unroll
  for (int i = 0; i < 2; ++i)
    #pragma unroll
    for (int j = 0; j < 2; ++j) acc[i][j] = (f32x4){0.f, 0.f, 0.f, 0.f};

  for (int k0 = 0; k0 < 1024; k0 += 128) {
    __syncthreads();   // prior MFMA ds_reads done before overwrite
    #pragma unroll
    for (int i = 0; i < 4; ++i) {
      int idx = i * 256 + t;            // uint4 slot
      int r = idx >> 4, ssw = idx & 15;
      int scol = ssw ^ (r & 7);
      gload16(qbf + (size_t)(m0 + r) * 1024 + k0 + scol * 8,
              (char*)As + (i * 256 + wid * 64) * 16);
      gload16(w2t + (size_t)(n0 + r) * 1024 + k0 + scol * 8,
              (char*)Bs + (i * 256 + wid * 64) * 16);
    }
    __syncthreads();   // drains vmcnt -> tiles complete
    #pragma unroll
    for (int kk = 0; kk < 4; ++kk) {
      short8v aF[2], bF[2];
      int sl = kk * 4 + (lane >> 4);
      #pragma unroll
      for (int fm = 0; fm < 2; ++fm)
        aF[fm] = frag16(As, wm * 32 + fm * 16 + (lane & 15), sl);
      #pragma unroll
      for (int fn = 0; fn < 2; ++fn)
        bF[fn] = frag16(Bs, wn * 32 + fn * 16 + (lane & 15), sl);
      #pragma unroll
      for (int fm = 0; fm < 2; ++fm)
        #pragma unroll
        for (int fn = 0; fn < 2; ++fn)
          acc[fm][fn] = __builtin_amdgcn_mfma_f32_16x16x32_bf16(aF[fm], bF[fn], acc[fm][fn], 0, 0, 0);
    }
  }
  int cn = lane & 15, rq = lane >> 4;
  #pragma unroll
  for (int fn = 0; fn < 2; ++fn) {
    int n = n0 + wn * 32 + fn * 16 + cn;
    float bias = b2[n];
    #pragma unroll
    for (int fm = 0; fm < 2; ++fm)
      #pragma unroll
      for (int j = 0; j < 4; ++j) {
        int m = m0 + wm * 32 + fm * 16 + rq * 4 + j;
        qt[(size_t)m * 512 + n] = f2bf(acc[fm][fn][j] + bias);
      }
  }
}

// ---------------- partial scores: S_part[dq][n][l] (XCD-swizzled) ----------------
// 1024 blocks: logical = (h&7)*128 + (h>>3); g = logical>>2, dq = logical&3.
// Each XCD gets 32 contiguous groups x all dq -> kbf/qt slices L2-resident.
// Fully async-staged (R14-validated), 1-term bf16 MFMA, LDS 12 KB.
__global__ __launch_bounds__(256) void k_scores4(
    const unsigned short* __restrict__ qt,
    const unsigned short* __restrict__ kbf, const int* __restrict__ starts,
    float* __restrict__ s_part) {
  int h = blockIdx.x;
  int logical = (h & 7) * 128 + (h >> 3);
  int g = logical >> 2, dq = logical & 3;
  int t = threadIdx.x, lane = t & 63, wl = t >> 6;
  int s0 = starts[g], s1 = starts[g + 1];
  if (s0 >= s1) return;

  __shared__ __align__(16) unsigned short Ks[64*64];   // 8 KB
  __shared__ __align__(16) unsigned short Qs[32*64];   // 4 KB

  float* sp = s_part + (size_t)dq * NQ * LL;

  for (int cs = s0; cs < s1; cs += 32) {
    int qc = min(32, s1 - cs);
    f32x4 acc[2];
    acc[0] = (f32x4){0.f,0.f,0.f,0.f};
    acc[1] = (f32x4){0.f,0.f,0.f,0.f};

    #pragma unroll
    for (int kt = 0; kt < 2; ++kt) {
      int k0 = dq * 128 + kt * 64;
      __syncthreads();
      // K tile: async, 2 uint4 slots/thread, pre-swizzled source col
      #pragma unroll
      for (int i = 0; i < 2; ++i) {
        int idx = i * 256 + t;
        int r = idx >> 3, ssw = idx & 7;
        int scol = ssw ^ (r & 7);
        gload16(kbf + ((size_t)g * LL + r) * DD + k0 + scol * 8,
                (char*)Ks + (i * 256 + wl * 64) * 16);
      }
      // Q tile: async, 1 slot/thread (wave wl covers slots wl*64..+63)
      {
        int r = t >> 3, ssw = t & 7;
        int scol = ssw ^ (r & 7);
        gload16(qt + (size_t)(cs + r) * DD + k0 + scol * 8,
                (char*)Qs + wl * 64 * 16);
      }
      __syncthreads();
      #pragma unroll
      for (int kk = 0; kk < 2; ++kk) {
        int sl = kk * 4 + (lane >> 4);
        short8v aF = frag(Ks, wl * 16 + (lane & 15), sl);
        #pragma unroll
        for (int fn = 0; fn < 2; ++fn) {
          short8v bF = frag(Qs, fn * 16 + (lane & 15), sl);
          acc[fn] = __builtin_amdgcn_mfma_f32_16x16x32_bf16(aF, bF, acc[fn], 0, 0, 0);
        }
      }
    }
    // write partial S (row-guarded)
    {
      int cq = lane & 15, rq = lane >> 4;
      #pragma unroll
      for (int fn = 0; fn < 2; ++fn) {
        int q = fn * 16 + cq;
        if (q < qc) {
          float* row = sp + (size_t)(cs + q) * LL;
          #pragma unroll
          for (int j = 0; j < 4; ++j)
            row[wl * 16 + rq * 4 + j] = acc[fn][j];
        }
      }
    }
  }
}

// ---------------- PV: sum partials + softmax + out (XCD-swizzled) ----------------
// 512 blocks: logical = (h&7)*64 + (h>>3); g = logical>>1, dh = logical&1.
__global__ __launch_bounds__(256) void k_pv2(
    const float* __restrict__ s_part, const float* __restrict__ vv_,
    const float* __restrict__ msk, const int* __restrict__ starts,
    float* __restrict__ out) {
  int h = blockIdx.x;
  int logical = (h & 7) * 64 + (h >> 3);
  int g = logical >> 1, dh = logical & 1;
  int t = threadIdx.x, lane = t & 63, wid = t >> 6;
  int s0 = starts[g], s1 = starts[g + 1];
  if (s0 >= s1) return;

  __shared__ __align__(16) float S_lds[32][68];   // 8.7 KB
  __shared__ float bias_lds[LL];
  if (t < LL) bias_lds[t] = __expf(50.0f * (1.0f - msk[g * LL + t])) - 1.0f;

  const float* vb = vv_ + (size_t)g * LL * DD + dh * 256 + lane * 4;

  for (int cs = s0; cs < s1; cs += 32) {
    int qc = min(32, s1 - cs);
    __syncthreads();
    #pragma unroll
    for (int i = 0; i < 2; ++i) {
      int f = i * 256 + t;
      int q = f >> 4, l4 = f & 15;
      const float* p = s_part + (size_t)(cs + q) * LL + l4 * 4;
      float4 a0 = *(const float4*)p;
      float4 a1 = *(const float4*)(p + (size_t)NQ * LL);
      float4 a2 = *(const float4*)(p + (size_t)2 * NQ * LL);
      float4 a3 = *(const float4*)(p + (size_t)3 * NQ * LL);
      float4 r;
      r.x = (a0.x + a1.x + a2.x + a3.x) * SCALE - bias_lds[l4 * 4 + 0];
      r.y = (a0.y + a1.y + a2.y + a3.y) * SCALE - bias_lds[l4 * 4 + 1];
      r.z = (a0.z + a1.z + a2.z + a3.z) * SCALE - bias_lds[l4 * 4 + 2];
      r.w = (a0.w + a1.w + a2.w + a3.w) * SCALE - bias_lds[l4 * 4 + 3];
      *(float4*)&S_lds[q][l4 * 4] = r;
    }
    __syncthreads();
    {
      int q = t >> 3, i = t & 7;
      float4 x0 = *(const float4*)&S_lds[q][i * 8];
      float4 x1 = *(const float4*)&S_lds[q][i * 8 + 4];
      float mx = fmaxf(fmaxf(fmaxf(x0.x, x0.y), fmaxf(x0.z, x0.w)),
                       fmaxf(fmaxf(x1.x, x1.y), fmaxf(x1.z, x1.w)));
      #pragma unroll
      for (int off = 1; off < 8; off <<= 1) mx = fmaxf(mx, __shfl_xor(mx, off, 8));
      float e0 = __expf(x0.x - mx), e1 = __expf(x0.y - mx);
      float e2 = __expf(x0.z - mx), e3 = __expf(x0.w - mx);
      float e4 = __expf(x1.x - mx), e5 = __expf(x1.y - mx);
      float e6 = __expf(x1.z - mx), e7 = __expf(x1.w - mx);
      float sum = ((e0 + e1) + (e2 + e3)) + ((e4 + e5) + (e6 + e7));
      #pragma unroll
      for (int off = 1; off < 8; off <<= 1) sum += __shfl_xor(sum, off, 8);
      float inv = 1.0f / sum;
      *(float4*)&S_lds[q][i * 8]     = make_float4(e0 * inv, e1 * inv, e2 * inv, e3 * inv);
      *(float4*)&S_lds[q][i * 8 + 4] = make_float4(e4 * inv, e5 * inv, e6 * inv, e7 * inv);
    }
    __syncthreads();
    {
      float o[8][4];
      #pragma unroll
      for (int u = 0; u < 8; ++u)
        #pragma unroll
        for (int e = 0; e < 4; ++e) o[u][e] = 0.f;
      for (int l0 = 0; l0 < LL; l0 += 4) {
        float a_[8][4];
        #pragma unroll
        for (int u = 0; u < 8; ++u) {
          float4 av = *(const float4*)&S_lds[wid * 8 + u][l0];
          a_[u][0] = av.x; a_[u][1] = av.y; a_[u][2] = av.z; a_[u][3] = av.w;
        }
        #pragma unroll
        for (int e = 0; e < 4; ++e) {
          float4 vv = *(const float4*)&vb[(size_t)(l0 + e) * DD];
          #pragma unroll
          for (int u = 0; u < 8; ++u) {
            o[u][0] += a_[u][e] * vv.x;
            o[u][1] += a_[u][e] * vv.y;
            o[u][2] += a_[u][e] * vv.z;
            o[u][3] += a_[u][e] * vv.w;
          }
        }
      }
      #pragma unroll
      for (int u = 0; u < 8; ++u) {
        int q = wid * 8 + u;
        if (q < qc) {
          *(float4*)&out[(size_t)(cs + q) * DD + dh * 256 + lane * 4] =
              make_float4(o[u][0], o[u][1], o[u][2], o[u][3]);
        }
      }
    }
  }
}

extern "C" void kernel_launch(void* const* d_in, const int* in_sizes, int n_in,
                              void* d_out, int out_size, void* d_ws, size_t ws_size,
                              hipStream_t stream) {
  const float* q_in = (const float*)d_in[0];
  const float* k_in = (const float*)d_in[1];
  const float* v_in = (const float*)d_in[2];
  const float* m_in = (const float*)d_in[3];
  const int*   gid  = (const int*)d_in[4];
  const float* Wq   = (const float*)d_in[5];
  const float* bq   = (const float*)d_in[6];
  const float* Wk   = (const float*)d_in[7];
  // d_in[8] = bk: per-query constant on all scores -> cancels in softmax.
  float* out = (float*)d_out;

  // ws: w2t[1MB] | qt[4MB] | qbf[8MB] | b2 | starts | s_part[4MB] | kbf[16.8MB]
  unsigned short* w2t = (unsigned short*)d_ws;
  unsigned short* qt  = w2t + 512 * 1024;
  unsigned short* qbf = qt + 4096 * 512;
  float* b2 = (float*)(qbf + 4096 * 1024);
  int* starts = (int*)(b2 + 512);
  float* s_part = (float*)(starts + 512);          // [4][4096][64]
  unsigned short* kbf = (unsigned short*)(s_part + 4 * NQ * LL);  // [256][64][512]

  // 1) prep: w2t (0-127) + qbf (128-2175) + starts (2176) + b2 (2177-2178)
  k_prep<<<2179, 256, 0, stream>>>(q_in, gid, Wk, Wq, bq, qbf, starts, b2, w2t);
  // 2) qt GEMM (XCD-swizzled, blocks 0-511) + K->bf16 conversion (512-4607)
  gemm_qt_mfma<<<4608, 256, 0, stream>>>(qbf, w2t, b2, qt, k_in, kbf);
  // 3) partial scores, fully async-staged, XCD-swizzled (1024 blocks)
  k_scores4<<<NGRP * 4, 256, 0, stream>>>(qt, kbf, starts, s_part);
  // 4) sum + softmax + PV, XCD-swizzled (512 blocks)
  k_pv2<<<NGRP * 2, 256, 0, stream>>>(s_part, v_in, m_in, starts, out);
}

// Round 17
// 59.909 us; speedup vs baseline: 1.3395x; 1.0081x over previous
//
#include <hip/hip_runtime.h>

#define NQ   4096
#define NGRP 256
#define LL   64
#define DD   512

typedef __attribute__((ext_vector_type(8))) short short8v;
typedef __attribute__((ext_vector_type(4))) float f32x4;
typedef __attribute__((ext_vector_type(4))) unsigned short us4v;

#define SCALE 0.044194173824159216f

// float -> bf16 bits, round-to-nearest-even
static __device__ __forceinline__ unsigned short f2bf(float f) {
  union { float f; unsigned u; } x{f};
  unsigned r = x.u + 0x7fffu + ((x.u >> 16) & 1u);
  return (unsigned short)(r >> 16);
}
static __device__ __forceinline__ float bf2f(unsigned short h) {
  union { unsigned u; float f; } x{(unsigned)h << 16};
  return x.f;
}

// async global->LDS 16B: lds dest is wave-uniform base + lane*16
static __device__ __forceinline__ void gload16(const void* g, void* lds_wave_base) {
  __builtin_amdgcn_global_load_lds(
      (const __attribute__((address_space(1))) void*)g,
      (__attribute__((address_space(3))) void*)lds_wave_base, 16, 0, 0);
}

// fp32 float4 pair -> packed 8 bf16 (uint4)
static __device__ __forceinline__ uint4 pack8(float4 f0, float4 f1) {
  uint4 pk;
  pk.x = (unsigned)f2bf(f0.x) | ((unsigned)f2bf(f0.y) << 16);
  pk.y = (unsigned)f2bf(f0.z) | ((unsigned)f2bf(f0.w) << 16);
  pk.z = (unsigned)f2bf(f1.x) | ((unsigned)f2bf(f1.y) << 16);
  pk.w = (unsigned)f2bf(f1.z) | ((unsigned)f2bf(f1.w) << 16);
  return pk;
}

// split fp32 float4 -> hi/lo bf16 into XOR-slot-swizzled LDS tile [rows][8 slots of us8]
static __device__ __forceinline__ void split_store(
    unsigned short* Hh, unsigned short* Hl, int r, int c4, float4 v) {
  int s = c4 >> 1, hf = c4 & 1;
  int base = (r * 8 + (s ^ (r & 7))) * 8 + hf * 4;
  unsigned short h0 = f2bf(v.x), h1 = f2bf(v.y), h2 = f2bf(v.z), h3 = f2bf(v.w);
  us4v hv = {h0, h1, h2, h3};
  us4v lv = {f2bf(v.x - bf2f(h0)), f2bf(v.y - bf2f(h1)),
             f2bf(v.z - bf2f(h2)), f2bf(v.w - bf2f(h3))};
  *(us4v*)(Hh + base) = hv;
  *(us4v*)(Hl + base) = lv;
}

// MFMA fragment load from swizzled LDS tile (8 slots/row)
static __device__ __forceinline__ short8v frag(const unsigned short* P, int r, int sl) {
  return *(const short8v*)(P + (r * 8 + (sl ^ (r & 7))) * 8);
}
// 16 slots/row variant (128-wide tiles); XOR acts on low 3 slot bits
static __device__ __forceinline__ short8v frag16(const unsigned short* P, int r, int sl) {
  return *(const short8v*)(P + (r * 16 + (sl ^ (r & 7))) * 8);
}

// ---------------- merged prep (R13-validated layout, unchanged) ----------------
// blocks [0,128): W2T = Wk @ Wq^T via 3-term split MFMA, single-bf16 output.
// blocks [128,2176): q fp32 -> bf16;  2176: starts;  2177-2178: b2 = Wk @ bq
__global__ __launch_bounds__(256) void k_prep(
    const float* __restrict__ q_in, const int* __restrict__ gid,
    const float* __restrict__ Wk, const float* __restrict__ Wq,
    const float* __restrict__ bq,
    unsigned short* __restrict__ qbf, int* __restrict__ starts,
    float* __restrict__ b2, unsigned short* __restrict__ w2t) {
  __shared__ __align__(16) unsigned short lds[4 * 64 * 64];  // 32 KB
  int b = blockIdx.x, t = threadIdx.x;
  if (b < 128) {
    unsigned short* Ah = lds;
    unsigned short* Al = lds + 4096;
    unsigned short* Bh = lds + 8192;
    unsigned short* Bl = lds + 12288;
    int lane = t & 63, wid = t >> 6;
    int wm = wid >> 1, wn = wid & 1;
    int n0 = (b & 15) * 64, m0 = (b >> 4) * 64;
    f32x4 acc[2][2];
    #pragma unroll
    for (int i = 0; i < 2; ++i)
      #pragma unroll
      for (int j = 0; j < 2; ++j) acc[i][j] = (f32x4){0.f,0.f,0.f,0.f};

    for (int k0 = 0; k0 < 512; k0 += 64) {
      __syncthreads();
      #pragma unroll
      for (int i = 0; i < 4; ++i) {
        int idx = i * 256 + t, r = idx >> 4, c4 = idx & 15;
        float4 vA = *(const float4*)&Wk[(size_t)(m0 + r) * 512 + k0 + c4 * 4];
        split_store(Ah, Al, r, c4, vA);
        float4 vB = *(const float4*)&Wq[(size_t)(n0 + r) * 512 + k0 + c4 * 4];
        split_store(Bh, Bl, r, c4, vB);
      }
      __syncthreads();
      #pragma unroll
      for (int kk = 0; kk < 2; ++kk) {
        int sl = kk * 4 + (lane >> 4);
        short8v aH[2], aL[2], bH[2], bL[2];
        #pragma unroll
        for (int fm = 0; fm < 2; ++fm) {
          int r = wm * 32 + fm * 16 + (lane & 15);
          aH[fm] = frag(Ah, r, sl); aL[fm] = frag(Al, r, sl);
        }
        #pragma unroll
        for (int fn = 0; fn < 2; ++fn) {
          int r = wn * 32 + fn * 16 + (lane & 15);
          bH[fn] = frag(Bh, r, sl); bL[fn] = frag(Bl, r, sl);
        }
        #pragma unroll
        for (int fm = 0; fm < 2; ++fm)
          #pragma unroll
          for (int fn = 0; fn < 2; ++fn) {
            acc[fm][fn] = __builtin_amdgcn_mfma_f32_16x16x32_bf16(aH[fm], bH[fn], acc[fm][fn], 0, 0, 0);
            acc[fm][fn] = __builtin_amdgcn_mfma_f32_16x16x32_bf16(aH[fm], bL[fn], acc[fm][fn], 0, 0, 0);
            acc[fm][fn] = __builtin_amdgcn_mfma_f32_16x16x32_bf16(aL[fm], bH[fn], acc[fm][fn], 0, 0, 0);
          }
      }
    }
    int cn = lane & 15, rq = lane >> 4;
    #pragma unroll
    for (int fm = 0; fm < 2; ++fm)
      #pragma unroll
      for (int fn = 0; fn < 2; ++fn)
        #pragma unroll
        for (int j = 0; j < 4; ++j) {
          int m = m0 + wm * 32 + fm * 16 + rq * 4 + j;
          int n = n0 + wn * 32 + fn * 16 + cn;
          w2t[(size_t)m * 1024 + n] = f2bf(acc[fm][fn][j]);
        }
  } else if (b < 2176) {
    int idx = (b - 128) * 256 + t;   // one uint4 (8 bf16) per thread
    const float* src = q_in + (size_t)idx * 8;
    ((uint4*)qbf)[idx] = pack8(*(const float4*)src, *(const float4*)(src + 4));
  } else if (b == 2176) {
    for (int g = t; g <= NGRP; g += 256) {
      int lo = 0, hi = NQ;
      while (lo < hi) { int mid = (lo + hi) >> 1; if (gid[mid] < g) lo = mid + 1; else hi = mid; }
      starts[g] = lo;
    }
  } else {
    int dd = (b - 2177) * 256 + t;
    if (dd < DD) {
      float s = 0.f;
      const float* row = Wk + (size_t)dd * DD;
      for (int j = 0; j < DD; j += 4) {
        float4 w = *(const float4*)&row[j];
        float4 bb = *(const float4*)&bq[j];
        s += w.x*bb.x + w.y*bb.y + w.z*bb.z + w.w*bb.w;
      }
      b2[dd] = s;
    }
  }
}

// ---------------- qt GEMM (XCD-swizzled) + K->bf16 conversion (trailing) ------
// (R15-validated, unchanged)
__global__ __launch_bounds__(256) void gemm_qt_mfma(
    const unsigned short* __restrict__ qbf,
    const unsigned short* __restrict__ w2t,
    const float* __restrict__ b2,
    unsigned short* __restrict__ qt,
    const float* __restrict__ k_in, unsigned short* __restrict__ kbf) {
  __shared__ __align__(16) unsigned short As[64 * 128];  // 16 KB
  __shared__ __align__(16) unsigned short Bs[64 * 128];  // 16 KB
  int b = blockIdx.x, t = threadIdx.x;

  if (b >= 512) {
    int idx = (b - 512) * 256 + t;   // one uint4 (8 bf16) per thread
    const float* src = k_in + (size_t)idx * 8;
    ((uint4*)kbf)[idx] = pack8(*(const float4*)src, *(const float4*)(src + 4));
    return;
  }

  int logical = (b & 7) * 64 + (b >> 3);       // bijective bit-permute
  int n0 = (logical & 7) * 64, m0 = (logical >> 3) * 64;
  int lane = t & 63, wid = t >> 6;
  int wm = wid >> 1, wn = wid & 1;

  f32x4 acc[2][2];
  #pragma unroll
  for (int i = 0; i < 2; ++i)
    #pragma unroll
    for (int j = 0; j < 2; ++j) acc[i][j] = (f32x4){0.f, 0.f, 0.f, 0.f};

  for (int k0 = 0; k0 < 1024; k0 += 128) {
    __syncthreads();   // prior MFMA ds_reads done before overwrite
    #pragma unroll
    for (int i = 0; i < 4; ++i) {
      int idx = i * 256 + t;            // uint4 slot
      int r = idx >> 4, ssw = idx & 15;
      int scol = ssw ^ (r & 7);
      gload16(qbf + (size_t)(m0 + r) * 1024 + k0 + scol * 8,
              (char*)As + (i * 256 + wid * 64) * 16);
      gload16(w2t + (size_t)(n0 + r) * 1024 + k0 + scol * 8,
              (char*)Bs + (i * 256 + wid * 64) * 16);
    }
    __syncthreads();   // drains vmcnt -> tiles complete
    #pragma unroll
    for (int kk = 0; kk < 4; ++kk) {
      short8v aF[2], bF[2];
      int sl = kk * 4 + (lane >> 4);
      #pragma unroll
      for (int fm = 0; fm < 2; ++fm)
        aF[fm] = frag16(As, wm * 32 + fm * 16 + (lane & 15), sl);
      #pragma unroll
      for (int fn = 0; fn < 2; ++fn)
        bF[fn] = frag16(Bs, wn * 32 + fn * 16 + (lane & 15), sl);
      #pragma unroll
      for (int fm = 0; fm < 2; ++fm)
        #pragma unroll
        for (int fn = 0; fn < 2; ++fn)
          acc[fm][fn] = __builtin_amdgcn_mfma_f32_16x16x32_bf16(aF[fm], bF[fn], acc[fm][fn], 0, 0, 0);
    }
  }
  int cn = lane & 15, rq = lane >> 4;
  #pragma unroll
  for (int fn = 0; fn < 2; ++fn) {
    int n = n0 + wn * 32 + fn * 16 + cn;
    float bias = b2[n];
    #pragma unroll
    for (int fm = 0; fm < 2; ++fm)
      #pragma unroll
      for (int j = 0; j < 4; ++j) {
        int m = m0 + wm * 32 + fm * 16 + rq * 4 + j;
        qt[(size_t)m * 512 + n] = f2bf(acc[fm][fn][j] + bias);
      }
  }
}

// ---------------- partial scores: S_part[dq][n][l] bf16 (XCD-swizzled) --------
// 1024 blocks: logical = (h&7)*128 + (h>>3); g = logical>>2, dq = logical&3.
// Single 128-wide staging round per chunk: Ks 64x128 = 1024 uint4 slots
// (4 loads/thread), Qs 32x128 = 512 slots (2 loads/thread). Fully async-staged;
// 1-term bf16 MFMA; partials written as bf16. LDS 24 KB.
__global__ __launch_bounds__(256) void k_scores4(
    const unsigned short* __restrict__ qt,
    const unsigned short* __restrict__ kbf, const int* __restrict__ starts,
    unsigned short* __restrict__ s_part) {
  int h = blockIdx.x;
  int logical = (h & 7) * 128 + (h >> 3);
  int g = logical >> 2, dq = logical & 3;
  int t = threadIdx.x, lane = t & 63, wl = t >> 6;
  int s0 = starts[g], s1 = starts[g + 1];
  if (s0 >= s1) return;

  __shared__ __align__(16) unsigned short Ks[64 * 128];  // 16 KB = 1024 uint4
  __shared__ __align__(16) unsigned short Qs[32 * 128];  // 8 KB = 512 uint4

  unsigned short* sp = s_part + (size_t)dq * NQ * LL;
  int k0 = dq * 128;

  for (int cs = s0; cs < s1; cs += 32) {
    int qc = min(32, s1 - cs);
    f32x4 acc[2];
    acc[0] = (f32x4){0.f,0.f,0.f,0.f};
    acc[1] = (f32x4){0.f,0.f,0.f,0.f};

    __syncthreads();   // prior chunk's MFMA ds_reads done before overwrite
    // K tile 64x128: 1024 uint4 slots, 4/thread, pre-swizzled source col
    #pragma unroll
    for (int i = 0; i < 4; ++i) {
      int idx = i * 256 + t;
      int r = idx >> 4, ssw = idx & 15;
      int scol = ssw ^ (r & 7);
      gload16(kbf + ((size_t)g * LL + r) * DD + k0 + scol * 8,
              (char*)Ks + (i * 256 + wl * 64) * 16);
    }
    // Q tile 32x128: 512 uint4 slots, 2/thread (rows >= qc read neighbor data;
    // outputs guarded)
    #pragma unroll
    for (int i = 0; i < 2; ++i) {
      int idx = i * 256 + t;
      int r = idx >> 4, ssw = idx & 15;
      int scol = ssw ^ (r & 7);
      gload16(qt + (size_t)(cs + r) * DD + k0 + scol * 8,
              (char*)Qs + (i * 256 + wl * 64) * 16);
    }
    __syncthreads();   // drains vmcnt -> tiles complete
    #pragma unroll
    for (int kk = 0; kk < 4; ++kk) {
      int sl = kk * 4 + (lane >> 4);
      short8v aF = frag16(Ks, wl * 16 + (lane & 15), sl);
      #pragma unroll
      for (int fn = 0; fn < 2; ++fn) {
        short8v bF = frag16(Qs, fn * 16 + (lane & 15), sl);
        acc[fn] = __builtin_amdgcn_mfma_f32_16x16x32_bf16(aF, bF, acc[fn], 0, 0, 0);
      }
    }
    // write partial S as bf16 (row-guarded)
    {
      int cq = lane & 15, rq = lane >> 4;
      #pragma unroll
      for (int fn = 0; fn < 2; ++fn) {
        int q = fn * 16 + cq;
        if (q < qc) {
          us4v w = { f2bf(acc[fn][0]), f2bf(acc[fn][1]),
                     f2bf(acc[fn][2]), f2bf(acc[fn][3]) };
          *(us4v*)(sp + (size_t)(cs + q) * LL + wl * 16 + rq * 4) = w;
        }
      }
    }
  }
}

// ---------------- PV: sum bf16 partials + softmax + out (XCD-swizzled) --------
// 512 blocks: logical = (h&7)*64 + (h>>3); g = logical>>1, dh = logical&1.
__global__ __launch_bounds__(256) void k_pv2(
    const unsigned short* __restrict__ s_part, const float* __restrict__ vv_,
    const float* __restrict__ msk, const int* __restrict__ starts,
    float* __restrict__ out) {
  int h = blockIdx.x;
  int logical = (h & 7) * 64 + (h >> 3);
  int g = logical >> 1, dh = logical & 1;
  int t = threadIdx.x, lane = t & 63, wid = t >> 6;
  int s0 = starts[g], s1 = starts[g + 1];
  if (s0 >= s1) return;

  __shared__ __align__(16) float S_lds[32][68];   // 8.7 KB
  __shared__ float bias_lds[LL];
  if (t < LL) bias_lds[t] = __expf(50.0f * (1.0f - msk[g * LL + t])) - 1.0f;

  const float* vb = vv_ + (size_t)g * LL * DD + dh * 256 + lane * 4;

  for (int cs = s0; cs < s1; cs += 32) {
    int qc = min(32, s1 - cs);
    __syncthreads();
    // sum 4 bf16 quarters + scale + bias -> S_lds[q][l]
    #pragma unroll
    for (int i = 0; i < 2; ++i) {
      int f = i * 256 + t;
      int q = f >> 4, l4 = f & 15;
      const unsigned short* p = s_part + (size_t)(cs + q) * LL + l4 * 4;
      us4v a0 = *(const us4v*)p;
      us4v a1 = *(const us4v*)(p + (size_t)NQ * LL);
      us4v a2 = *(const us4v*)(p + (size_t)2 * NQ * LL);
      us4v a3 = *(const us4v*)(p + (size_t)3 * NQ * LL);
      float4 r;
      r.x = (bf2f(a0[0]) + bf2f(a1[0]) + bf2f(a2[0]) + bf2f(a3[0])) * SCALE - bias_lds[l4 * 4 + 0];
      r.y = (bf2f(a0[1]) + bf2f(a1[1]) + bf2f(a2[1]) + bf2f(a3[1])) * SCALE - bias_lds[l4 * 4 + 1];
      r.z = (bf2f(a0[2]) + bf2f(a1[2]) + bf2f(a2[2]) + bf2f(a3[2])) * SCALE - bias_lds[l4 * 4 + 2];
      r.w = (bf2f(a0[3]) + bf2f(a1[3]) + bf2f(a2[3]) + bf2f(a3[3])) * SCALE - bias_lds[l4 * 4 + 3];
      *(float4*)&S_lds[q][l4 * 4] = r;
    }
    __syncthreads();
    // softmax per q over 64 l: 32 q x 8 lanes
    {
      int q = t >> 3, i = t & 7;
      float4 x0 = *(const float4*)&S_lds[q][i * 8];
      float4 x1 = *(const float4*)&S_lds[q][i * 8 + 4];
      float mx = fmaxf(fmaxf(fmaxf(x0.x, x0.y), fmaxf(x0.z, x0.w)),
                       fmaxf(fmaxf(x1.x, x1.y), fmaxf(x1.z, x1.w)));
      #pragma unroll
      for (int off = 1; off < 8; off <<= 1) mx = fmaxf(mx, __shfl_xor(mx, off, 8));
      float e0 = __expf(x0.x - mx), e1 = __expf(x0.y - mx);
      float e2 = __expf(x0.z - mx), e3 = __expf(x0.w - mx);
      float e4 = __expf(x1.x - mx), e5 = __expf(x1.y - mx);
      float e6 = __expf(x1.z - mx), e7 = __expf(x1.w - mx);
      float sum = ((e0 + e1) + (e2 + e3)) + ((e4 + e5) + (e6 + e7));
      #pragma unroll
      for (int off = 1; off < 8; off <<= 1) sum += __shfl_xor(sum, off, 8);
      float inv = 1.0f / sum;
      *(float4*)&S_lds[q][i * 8]     = make_float4(e0 * inv, e1 * inv, e2 * inv, e3 * inv);
      *(float4*)&S_lds[q][i * 8 + 4] = make_float4(e4 * inv, e5 * inv, e6 * inv, e7 * inv);
    }
    __syncthreads();
    // PV: wave wid -> queries wid*8..+7; lane -> d = dh*256 + lane*4..+3
    {
      float o[8][4];
      #pragma unroll
      for (int u = 0; u < 8; ++u)
        #pragma unroll
        for (int e = 0; e < 4; ++e) o[u][e] = 0.f;
      for (int l0 = 0; l0 < LL; l0 += 4) {
        float a_[8][4];
        #pragma unroll
        for (int u = 0; u < 8; ++u) {
          float4 av = *(const float4*)&S_lds[wid * 8 + u][l0];
          a_[u][0] = av.x; a_[u][1] = av.y; a_[u][2] = av.z; a_[u][3] = av.w;
        }
        #pragma unroll
        for (int e = 0; e < 4; ++e) {
          float4 vv = *(const float4*)&vb[(size_t)(l0 + e) * DD];
          #pragma unroll
          for (int u = 0; u < 8; ++u) {
            o[u][0] += a_[u][e] * vv.x;
            o[u][1] += a_[u][e] * vv.y;
            o[u][2] += a_[u][e] * vv.z;
            o[u][3] += a_[u][e] * vv.w;
          }
        }
      }
      #pragma unroll
      for (int u = 0; u < 8; ++u) {
        int q = wid * 8 + u;
        if (q < qc) {
          *(float4*)&out[(size_t)(cs + q) * DD + dh * 256 + lane * 4] =
              make_float4(o[u][0], o[u][1], o[u][2], o[u][3]);
        }
      }
    }
  }
}

extern "C" void kernel_launch(void* const* d_in, const int* in_sizes, int n_in,
                              void* d_out, int out_size, void* d_ws, size_t ws_size,
                              hipStream_t stream) {
  const float* q_in = (const float*)d_in[0];
  const float* k_in = (const float*)d_in[1];
  const float* v_in = (const float*)d_in[2];
  const float* m_in = (const float*)d_in[3];
  const int*   gid  = (const int*)d_in[4];
  const float* Wq   = (const float*)d_in[5];
  const float* bq   = (const float*)d_in[6];
  const float* Wk   = (const float*)d_in[7];
  // d_in[8] = bk: per-query constant on all scores -> cancels in softmax.
  float* out = (float*)d_out;

  // ws: w2t[1MB] | qt[4MB] | qbf[8MB] | b2 | starts | s_part bf16[2MB] | kbf[16.8MB]
  unsigned short* w2t = (unsigned short*)d_ws;
  unsigned short* qt  = w2t + 512 * 1024;
  unsigned short* qbf = qt + 4096 * 512;
  float* b2 = (float*)(qbf + 4096 * 1024);
  int* starts = (int*)(b2 + 512);
  unsigned short* s_part = (unsigned short*)(starts + 512);   // [4][4096][64] bf16
  unsigned short* kbf = s_part + 4 * NQ * LL;                 // [256][64][512] bf16

  // 1) prep: w2t (0-127) + qbf (128-2175) + starts (2176) + b2 (2177-2178)
  k_prep<<<2179, 256, 0, stream>>>(q_in, gid, Wk, Wq, bq, qbf, starts, b2, w2t);
  // 2) qt GEMM (XCD-swizzled, blocks 0-511) + K->bf16 conversion (512-4607)
  gemm_qt_mfma<<<4608, 256, 0, stream>>>(qbf, w2t, b2, qt, k_in, kbf);
  // 3) partial scores, single-round async staging, bf16 partials (1024 blocks)
  k_scores4<<<NGRP * 4, 256, 0, stream>>>(qt, kbf, starts, s_part);
  // 4) sum + softmax + PV, XCD-swizzled (512 blocks)
  k_pv2<<<NGRP * 2, 256, 0, stream>>>(s_part, v_in, m_in, starts, out);
}